// Round 1
// baseline (1085.009 us; speedup 1.0000x reference)
//
#include <hip/hip_runtime.h>
#include <hip/hip_bf16.h>
#include <math.h>

#define BATCH 32
#define INC 1024
#define MIDC 256
#define SC 256
#define HW 784
#define KSEL 196   // int(0.25 * 784)

// ---------------- block reduce helpers (256 threads = 4 waves of 64) -------
__device__ inline float block_reduce(float v, volatile float* red, int tid, int op /*0=sum,1=max*/) {
    #pragma unroll
    for (int off = 32; off > 0; off >>= 1) {
        float o = __shfl_down(v, off, 64);
        v = op ? fmaxf(v, o) : (v + o);
    }
    __syncthreads();                 // protect red[] from previous reduction's readers
    if ((tid & 63) == 0) red[tid >> 6] = v;
    __syncthreads();
    return op ? fmaxf(fmaxf(red[0], red[1]), fmaxf(red[2], red[3]))
              : (red[0] + red[1] + red[2] + red[3]);
}

// ---------------- Kernel A: u[b][m] = Wq_b[m] + sum_s s[b][s]*Uq_w[m][s] ---
__global__ __launch_bounds__(256) void calc_u(const float* __restrict__ s,
                                              const float* __restrict__ Uq_w,
                                              const float* __restrict__ Wq_b,
                                              float* __restrict__ u) {
    __shared__ float ssh[SC];
    int b = blockIdx.x, m = threadIdx.x;
    ssh[m] = s[b * SC + m];
    __syncthreads();
    float acc = Wq_b[m];
    const float* uq = Uq_w + (size_t)m * SC;
    #pragma unroll 8
    for (int i = 0; i < SC; ++i) acc += ssh[i] * uq[i];
    u[b * MIDC + m] = acc;
}

// ---------------- Kernel B: sig[b,m,n] = stanh( Wq·X_b + u[b,m] ) ----------
// Per b: C[m=256, n=784] = Wq[256,1024] · X_b[1024,784]; 64x64 tile, K-step 16.
__global__ __launch_bounds__(256) void gemm1_stanh(const float* __restrict__ x,
                                                   const float* __restrict__ Wq,
                                                   const float* __restrict__ u,
                                                   float* __restrict__ sig) {
    int b  = blockIdx.z;
    int m0 = blockIdx.y * 64;
    int n0 = blockIdx.x * 64;
    __shared__ float As[64][17];
    __shared__ float Bs[16][68];
    int tid = threadIdx.x;
    int tx = tid & 15, ty = tid >> 4;
    float acc[4][4] = {};
    const float* Xb = x + (size_t)b * INC * HW;

    for (int k0 = 0; k0 < INC; k0 += 16) {
        {   // A tile: 64 rows (m) x 16 cols (k); thread loads float4 along k
            int ml = tid >> 2, kl = (tid & 3) * 4;
            const float4 av = *reinterpret_cast<const float4*>(Wq + (size_t)(m0 + ml) * INC + k0 + kl);
            As[ml][kl + 0] = av.x; As[ml][kl + 1] = av.y;
            As[ml][kl + 2] = av.z; As[ml][kl + 3] = av.w;
        }
        {   // B tile: 16 rows (k) x 64 cols (n); thread loads float4 along n
            int kl = tid >> 4, nl = (tid & 15) * 4;
            int n = n0 + nl;
            float4 bv = make_float4(0.f, 0.f, 0.f, 0.f);
            if (n < HW)  // n multiple of 4 and HW%4==0 -> full float4 in-bounds
                bv = *reinterpret_cast<const float4*>(Xb + (size_t)(k0 + kl) * HW + n);
            Bs[kl][nl + 0] = bv.x; Bs[kl][nl + 1] = bv.y;
            Bs[kl][nl + 2] = bv.z; Bs[kl][nl + 3] = bv.w;
        }
        __syncthreads();
        #pragma unroll
        for (int kk = 0; kk < 16; ++kk) {
            float a[4], bb[4];
            #pragma unroll
            for (int i = 0; i < 4; ++i) a[i] = As[ty * 4 + i][kk];
            #pragma unroll
            for (int j = 0; j < 4; ++j) bb[j] = Bs[kk][tx * 4 + j];
            #pragma unroll
            for (int i = 0; i < 4; ++i)
                #pragma unroll
                for (int j = 0; j < 4; ++j)
                    acc[i][j] += a[i] * bb[j];
        }
        __syncthreads();
    }
    const float* ub = u + b * MIDC;
    #pragma unroll
    for (int i = 0; i < 4; ++i) {
        int m = m0 + ty * 4 + i;
        float uu = ub[m];
        #pragma unroll
        for (int j = 0; j < 4; ++j) {
            int n = n0 + tx * 4 + j;
            if (n < HW) {
                float p = acc[i][j] + uu;
                sig[((size_t)b * MIDC + m) * HW + n] = 1.7159f * tanhf(0.66666667f * p);
            }
        }
    }
}

// ---------------- Kernel C: alpha[b,c,n] = w_w[c,:]·sig_b[:,n] + w_b[c] ----
// Per b: C[c=1024, n=784] = Ww[1024,256] · sig_b[256,784]; writes into d_out atten slot.
__global__ __launch_bounds__(256) void gemm2_bias(const float* __restrict__ sig,
                                                  const float* __restrict__ Ww,
                                                  const float* __restrict__ wb,
                                                  float* __restrict__ alpha) {
    int b  = blockIdx.z;
    int c0 = blockIdx.y * 64;
    int n0 = blockIdx.x * 64;
    __shared__ float As[64][17];
    __shared__ float Bs[16][68];
    int tid = threadIdx.x;
    int tx = tid & 15, ty = tid >> 4;
    float acc[4][4] = {};
    const float* Sb = sig + (size_t)b * MIDC * HW;

    for (int k0 = 0; k0 < MIDC; k0 += 16) {
        {
            int cl = tid >> 2, kl = (tid & 3) * 4;
            const float4 av = *reinterpret_cast<const float4*>(Ww + (size_t)(c0 + cl) * MIDC + k0 + kl);
            As[cl][kl + 0] = av.x; As[cl][kl + 1] = av.y;
            As[cl][kl + 2] = av.z; As[cl][kl + 3] = av.w;
        }
        {
            int kl = tid >> 4, nl = (tid & 15) * 4;
            int n = n0 + nl;
            float4 bv = make_float4(0.f, 0.f, 0.f, 0.f);
            if (n < HW)
                bv = *reinterpret_cast<const float4*>(Sb + (size_t)(k0 + kl) * HW + n);
            Bs[kl][nl + 0] = bv.x; Bs[kl][nl + 1] = bv.y;
            Bs[kl][nl + 2] = bv.z; Bs[kl][nl + 3] = bv.w;
        }
        __syncthreads();
        #pragma unroll
        for (int kk = 0; kk < 16; ++kk) {
            float a[4], bb[4];
            #pragma unroll
            for (int i = 0; i < 4; ++i) a[i] = As[ty * 4 + i][kk];
            #pragma unroll
            for (int j = 0; j < 4; ++j) bb[j] = Bs[kk][tx * 4 + j];
            #pragma unroll
            for (int i = 0; i < 4; ++i)
                #pragma unroll
                for (int j = 0; j < 4; ++j)
                    acc[i][j] += a[i] * bb[j];
        }
        __syncthreads();
    }
    #pragma unroll
    for (int i = 0; i < 4; ++i) {
        int c = c0 + ty * 4 + i;
        float bias = wb[c];
        #pragma unroll
        for (int j = 0; j < 4; ++j) {
            int n = n0 + tx * 4 + j;
            if (n < HW)
                alpha[((size_t)b * INC + c) * HW + n] = acc[i][j] + bias;
        }
    }
}

// ---------------- Kernel D: per-(b,c) row: topk th -> masked softmax -> dot
__global__ __launch_bounds__(256) void topk_softmax_reduce(const float* __restrict__ x,
                                                           float* __restrict__ out) {
    int row = blockIdx.x;                          // b*1024 + c
    float* arow = out + BATCH * INC + (size_t)row * HW;  // alpha in, atten out
    const float* xrow = x + (size_t)row * HW;      // x is [B,C,HW] flat = [32768,784]
    __shared__ float sb[1024];
    __shared__ float av[HW];
    __shared__ float red[4];
    int tid = threadIdx.x;

    for (int i = tid; i < 1024; i += 256) {
        float v = (i < HW) ? arow[i] : -INFINITY;
        sb[i] = v;
        if (i < HW) av[i] = v;
    }
    __syncthreads();

    // bitonic sort ascending, 1024 elems
    for (int k = 2; k <= 1024; k <<= 1) {
        for (int j = k >> 1; j > 0; j >>= 1) {
            for (int t = tid; t < 1024; t += 256) {
                int ixj = t ^ j;
                if (ixj > t) {
                    float a = sb[t], b2 = sb[ixj];
                    bool up = ((t & k) == 0);
                    if ((a > b2) == up) { sb[t] = b2; sb[ixj] = a; }
                }
            }
            __syncthreads();
        }
    }
    float th = sb[1024 - KSEL];   // 196th largest of the 784 real values

    // mask (strictly below th -> 0), then max
    float lmax = -INFINITY;
    for (int i = tid; i < HW; i += 256) {
        float v = av[i];
        v = (v < th) ? 0.0f : v;
        av[i] = v;
        lmax = fmaxf(lmax, v);
    }
    float mx = block_reduce(lmax, red, tid, 1);

    // exp and sum
    float lsum = 0.f;
    for (int i = tid; i < HW; i += 256) {
        float e = expf(av[i] - mx);
        av[i] = e;
        lsum += e;
    }
    float total = block_reduce(lsum, red, tid, 0);
    float inv = 1.0f / total;

    // atten write + weighted reduce
    float ldot = 0.f;
    for (int i = tid; i < HW; i += 256) {
        float a = av[i] * inv;
        arow[i] = a;
        ldot += xrow[i] * a;
    }
    float dot = block_reduce(ldot, red, tid, 0);
    if (tid == 0) out[row] = dot;
}

extern "C" void kernel_launch(void* const* d_in, const int* in_sizes, int n_in,
                              void* d_out, int out_size, void* d_ws, size_t ws_size,
                              hipStream_t stream) {
    const float* x    = (const float*)d_in[0];
    const float* s    = (const float*)d_in[1];
    const float* Wq_w = (const float*)d_in[2];
    const float* Wq_b = (const float*)d_in[3];
    const float* Uq_w = (const float*)d_in[4];
    const float* w_w  = (const float*)d_in[5];
    const float* w_b  = (const float*)d_in[6];
    float* out = (float*)d_out;

    float* u   = (float*)d_ws;                 // [32,256]
    float* sig = u + BATCH * MIDC;             // [32,256,784]  (~25.7 MB)
    float* alpha = out + BATCH * INC;          // alpha staged in atten slot of d_out

    calc_u<<<BATCH, 256, 0, stream>>>(s, Uq_w, Wq_b, u);
    gemm1_stanh<<<dim3((HW + 63) / 64, MIDC / 64, BATCH), 256, 0, stream>>>(x, Wq_w, u, sig);
    gemm2_bias<<<dim3((HW + 63) / 64, INC / 64, BATCH), 256, 0, stream>>>(sig, w_w, w_b, alpha);
    topk_softmax_reduce<<<BATCH * INC, 256, 0, stream>>>(x, out);
}

// Round 2
// 529.894 us; speedup vs baseline: 2.0476x; 2.0476x over previous
//
#include <hip/hip_runtime.h>
#include <hip/hip_bf16.h>
#include <math.h>

#define BATCH 32
#define INC 1024
#define MIDC 256
#define SC 256
#define HW 784
#define KSEL 196   // int(0.25 * 784)
#define NV 13      // ceil(784/64) values per lane

// ---------------- Kernel A: u[b][m] = Wq_b[m] + sum_s s[b][s]*Uq_w[m][s] ---
__global__ __launch_bounds__(256) void calc_u(const float* __restrict__ s,
                                              const float* __restrict__ Uq_w,
                                              const float* __restrict__ Wq_b,
                                              float* __restrict__ u) {
    __shared__ float ssh[SC];
    int b = blockIdx.x, m = threadIdx.x;
    ssh[m] = s[b * SC + m];
    __syncthreads();
    float acc = Wq_b[m];
    const float* uq = Uq_w + (size_t)m * SC;
    #pragma unroll 8
    for (int i = 0; i < SC; ++i) acc += ssh[i] * uq[i];
    u[b * MIDC + m] = acc;
}

// ---------------- Kernel B: sig[b,m,n] = stanh( Wq·X_b + u[b,m] ) ----------
__global__ __launch_bounds__(256) void gemm1_stanh(const float* __restrict__ x,
                                                   const float* __restrict__ Wq,
                                                   const float* __restrict__ u,
                                                   float* __restrict__ sig) {
    int b  = blockIdx.z;
    int m0 = blockIdx.y * 64;
    int n0 = blockIdx.x * 64;
    __shared__ float As[64][17];
    __shared__ float Bs[16][68];
    int tid = threadIdx.x;
    int tx = tid & 15, ty = tid >> 4;
    float acc[4][4] = {};
    const float* Xb = x + (size_t)b * INC * HW;

    for (int k0 = 0; k0 < INC; k0 += 16) {
        {
            int ml = tid >> 2, kl = (tid & 3) * 4;
            const float4 av = *reinterpret_cast<const float4*>(Wq + (size_t)(m0 + ml) * INC + k0 + kl);
            As[ml][kl + 0] = av.x; As[ml][kl + 1] = av.y;
            As[ml][kl + 2] = av.z; As[ml][kl + 3] = av.w;
        }
        {
            int kl = tid >> 4, nl = (tid & 15) * 4;
            int n = n0 + nl;
            float4 bv = make_float4(0.f, 0.f, 0.f, 0.f);
            if (n < HW)
                bv = *reinterpret_cast<const float4*>(Xb + (size_t)(k0 + kl) * HW + n);
            Bs[kl][nl + 0] = bv.x; Bs[kl][nl + 1] = bv.y;
            Bs[kl][nl + 2] = bv.z; Bs[kl][nl + 3] = bv.w;
        }
        __syncthreads();
        #pragma unroll
        for (int kk = 0; kk < 16; ++kk) {
            float a[4], bb[4];
            #pragma unroll
            for (int i = 0; i < 4; ++i) a[i] = As[ty * 4 + i][kk];
            #pragma unroll
            for (int j = 0; j < 4; ++j) bb[j] = Bs[kk][tx * 4 + j];
            #pragma unroll
            for (int i = 0; i < 4; ++i)
                #pragma unroll
                for (int j = 0; j < 4; ++j)
                    acc[i][j] += a[i] * bb[j];
        }
        __syncthreads();
    }
    const float* ub = u + b * MIDC;
    #pragma unroll
    for (int i = 0; i < 4; ++i) {
        int m = m0 + ty * 4 + i;
        float uu = ub[m];
        #pragma unroll
        for (int j = 0; j < 4; ++j) {
            int n = n0 + tx * 4 + j;
            if (n < HW) {
                float p = acc[i][j] + uu;
                sig[((size_t)b * MIDC + m) * HW + n] = 1.7159f * tanhf(0.66666667f * p);
            }
        }
    }
}

// ---------------- Kernel C: alpha[b,c,n] = w_w[c,:]·sig_b[:,n] + w_b[c] ----
__global__ __launch_bounds__(256) void gemm2_bias(const float* __restrict__ sig,
                                                  const float* __restrict__ Ww,
                                                  const float* __restrict__ wb,
                                                  float* __restrict__ alpha) {
    int b  = blockIdx.z;
    int c0 = blockIdx.y * 64;
    int n0 = blockIdx.x * 64;
    __shared__ float As[64][17];
    __shared__ float Bs[16][68];
    int tid = threadIdx.x;
    int tx = tid & 15, ty = tid >> 4;
    float acc[4][4] = {};
    const float* Sb = sig + (size_t)b * MIDC * HW;

    for (int k0 = 0; k0 < MIDC; k0 += 16) {
        {
            int cl = tid >> 2, kl = (tid & 3) * 4;
            const float4 av = *reinterpret_cast<const float4*>(Ww + (size_t)(c0 + cl) * MIDC + k0 + kl);
            As[cl][kl + 0] = av.x; As[cl][kl + 1] = av.y;
            As[cl][kl + 2] = av.z; As[cl][kl + 3] = av.w;
        }
        {
            int kl = tid >> 4, nl = (tid & 15) * 4;
            int n = n0 + nl;
            float4 bv = make_float4(0.f, 0.f, 0.f, 0.f);
            if (n < HW)
                bv = *reinterpret_cast<const float4*>(Sb + (size_t)(k0 + kl) * HW + n);
            Bs[kl][nl + 0] = bv.x; Bs[kl][nl + 1] = bv.y;
            Bs[kl][nl + 2] = bv.z; Bs[kl][nl + 3] = bv.w;
        }
        __syncthreads();
        #pragma unroll
        for (int kk = 0; kk < 16; ++kk) {
            float a[4], bb[4];
            #pragma unroll
            for (int i = 0; i < 4; ++i) a[i] = As[ty * 4 + i][kk];
            #pragma unroll
            for (int j = 0; j < 4; ++j) bb[j] = Bs[kk][tx * 4 + j];
            #pragma unroll
            for (int i = 0; i < 4; ++i)
                #pragma unroll
                for (int j = 0; j < 4; ++j)
                    acc[i][j] += a[i] * bb[j];
        }
        __syncthreads();
    }
    #pragma unroll
    for (int i = 0; i < 4; ++i) {
        int c = c0 + ty * 4 + i;
        float bias = wb[c];
        #pragma unroll
        for (int j = 0; j < 4; ++j) {
            int n = n0 + tx * 4 + j;
            if (n < HW)
                alpha[((size_t)b * INC + c) * HW + n] = acc[i][j] + bias;
        }
    }
}

// ---------------- Kernel D: per-(b,c) row: exact radix-select -> masked softmax -> dot
// One wave per row; 4 rows per 256-thread block. Values live in registers.
__global__ __launch_bounds__(256) void topk_softmax_reduce(const float* __restrict__ x,
                                                           float* __restrict__ out) {
    const int wid  = threadIdx.x >> 6;
    const int lane = threadIdx.x & 63;
    const int row  = blockIdx.x * 4 + wid;          // < 32768
    float* arow = out + BATCH * INC + (size_t)row * HW;
    const float* xrow = x + (size_t)row * HW;

    __shared__ int hist[4][256];

    // Load row into registers; build order-preserving uint keys.
    float    v[NV];
    uint32_t key[NV];
    #pragma unroll
    for (int i = 0; i < NV; ++i) {
        int n = lane + 64 * i;
        bool ok = (n < HW);
        float f = ok ? arow[n] : 0.0f;
        v[i] = f;
        uint32_t uu = __float_as_uint(f);
        uint32_t k = (uu & 0x80000000u) ? ~uu : (uu | 0x80000000u);
        key[i] = ok ? k : 0u;   // 0 sorts below every real fp32 key
    }

    // 4-round radix select for the KSEL-th largest key (exact).
    int kk = KSEL;
    uint32_t prefix = 0;
    #pragma unroll
    for (int round = 0; round < 4; ++round) {
        const int shift = 24 - 8 * round;
        const uint32_t himask = (round == 0) ? 0u : (0xFFFFFFFFu << (shift + 8));

        #pragma unroll
        for (int j = 0; j < 4; ++j) hist[wid][lane + 64 * j] = 0;
        __syncthreads();

        #pragma unroll
        for (int i = 0; i < NV; ++i) {
            if ((key[i] & himask) == prefix)
                atomicAdd(&hist[wid][(key[i] >> shift) & 255], 1);
        }
        __syncthreads();

        // lane owns bins [4*lane, 4*lane+3]; suffix-scan group sums across lanes
        int h0 = hist[wid][4 * lane + 0];
        int h1 = hist[wid][4 * lane + 1];
        int h2 = hist[wid][4 * lane + 2];
        int h3 = hist[wid][4 * lane + 3];
        int g  = h0 + h1 + h2 + h3;
        int suf = g;
        #pragma unroll
        for (int off = 1; off < 64; off <<= 1) {
            int o = __shfl_down(suf, off, 64);
            suf += (lane + off < 64) ? o : 0;
        }
        int ex = suf - g;                 // count of elems in bins > 4*lane+3
        int cgt3 = ex;
        int cgt2 = cgt3 + h3;
        int cgt1 = cgt2 + h2;
        int cgt0 = cgt1 + h1;
        int bsel = -1, cg = 0;
        if (cgt0 < kk && kk <= cgt0 + h0) { bsel = 4 * lane + 0; cg = cgt0; }
        if (cgt1 < kk && kk <= cgt1 + h1) { bsel = 4 * lane + 1; cg = cgt1; }
        if (cgt2 < kk && kk <= cgt2 + h2) { bsel = 4 * lane + 2; cg = cgt2; }
        if (cgt3 < kk && kk <= cgt3 + h3) { bsel = 4 * lane + 3; cg = cgt3; }
        unsigned long long m = __ballot(bsel >= 0);
        int src = (int)__ffsll((long long)m) - 1;
        bsel = __shfl(bsel, src, 64);
        cg   = __shfl(cg,   src, 64);
        kk -= cg;
        prefix |= ((uint32_t)bsel) << shift;
        __syncthreads();   // hist reused next round (uniform across waves)
    }

    // invert key -> float threshold (exact k-th largest value)
    uint32_t tu = (prefix & 0x80000000u) ? (prefix ^ 0x80000000u) : ~prefix;
    const float th = __uint_as_float(tu);

    // mask + max
    float mx = -INFINITY;
    #pragma unroll
    for (int i = 0; i < NV; ++i) {
        int n = lane + 64 * i;
        float f = v[i];
        f = (f < th) ? 0.0f : f;
        v[i] = f;
        if (n < HW) mx = fmaxf(mx, f);
    }
    #pragma unroll
    for (int off = 32; off; off >>= 1) mx = fmaxf(mx, __shfl_xor(mx, off, 64));

    // exp + sum
    float sum = 0.f;
    #pragma unroll
    for (int i = 0; i < NV; ++i) {
        int n = lane + 64 * i;
        float e = expf(v[i] - mx);
        v[i] = e;
        if (n < HW) sum += e;
    }
    #pragma unroll
    for (int off = 32; off; off >>= 1) sum += __shfl_xor(sum, off, 64);
    float inv = 1.0f / sum;

    // normalize, write atten, weighted reduce against x
    float dot = 0.f;
    #pragma unroll
    for (int i = 0; i < NV; ++i) {
        int n = lane + 64 * i;
        if (n < HW) {
            float a = v[i] * inv;
            arow[n] = a;
            dot += xrow[n] * a;
        }
    }
    #pragma unroll
    for (int off = 32; off; off >>= 1) dot += __shfl_xor(dot, off, 64);
    if (lane == 0) out[row] = dot;
}

extern "C" void kernel_launch(void* const* d_in, const int* in_sizes, int n_in,
                              void* d_out, int out_size, void* d_ws, size_t ws_size,
                              hipStream_t stream) {
    const float* x    = (const float*)d_in[0];
    const float* s    = (const float*)d_in[1];
    const float* Wq_w = (const float*)d_in[2];
    const float* Wq_b = (const float*)d_in[3];
    const float* Uq_w = (const float*)d_in[4];
    const float* w_w  = (const float*)d_in[5];
    const float* w_b  = (const float*)d_in[6];
    float* out = (float*)d_out;

    float* u   = (float*)d_ws;                 // [32,256]
    float* sig = u + BATCH * MIDC;             // [32,256,784]
    float* alpha = out + BATCH * INC;          // alpha staged in atten slot of d_out

    calc_u<<<BATCH, 256, 0, stream>>>(s, Uq_w, Wq_b, u);
    gemm1_stanh<<<dim3((HW + 63) / 64, MIDC / 64, BATCH), 256, 0, stream>>>(x, Wq_w, u, sig);
    gemm2_bias<<<dim3((HW + 63) / 64, INC / 64, BATCH), 256, 0, stream>>>(sig, w_w, w_b, alpha);
    topk_softmax_reduce<<<BATCH * INC / 4, 256, 0, stream>>>(x, out);
}

// Round 3
// 278.748 us; speedup vs baseline: 3.8924x; 1.9010x over previous
//
#include <hip/hip_runtime.h>
#include <hip/hip_bf16.h>
#include <math.h>

#define BATCH 32
#define INC 1024
#define MIDC 256
#define SC 256
#define HW 784
#define KSEL 196   // int(0.25 * 784)
#define NV 13      // ceil(784/64)

typedef unsigned short u16;
typedef __attribute__((ext_vector_type(8))) short bfrag;   // 8 bf16 (4 VGPRs)
typedef __attribute__((ext_vector_type(4))) float f4;      // 4 fp32 acc

struct alignas(8) us4 { u16 x, y, z, w; };

__device__ inline u16 bf16_rn(float f) {
    uint32_t u = __float_as_uint(f);
    u += 0x7FFFu + ((u >> 16) & 1u);
    return (u16)(u >> 16);
}
__device__ inline void split2(float f, u16& hi, u16& lo) {
    u16 h = bf16_rn(f);
    float fh = __uint_as_float(((uint32_t)h) << 16);
    hi = h;
    lo = bf16_rn(f - fh);
}

// ---------------- split fp32 weights into bf16 hi/lo (layout preserved) ----
__global__ __launch_bounds__(256) void split_pairs(const float* __restrict__ src,
                                                   u16* __restrict__ hi,
                                                   u16* __restrict__ lo, int n4) {
    int i = blockIdx.x * 256 + threadIdx.x;
    if (i >= n4) return;
    float4 v = ((const float4*)src)[i];
    us4 h, l;
    split2(v.x, h.x, l.x); split2(v.y, h.y, l.y);
    split2(v.z, h.z, l.z); split2(v.w, h.w, l.w);
    ((us4*)hi)[i] = h; ((us4*)lo)[i] = l;
}

// ---------------- transpose x[b][c][n] -> xt[b][n][c] as bf16 hi/lo --------
__global__ __launch_bounds__(256) void prep_x(const float* __restrict__ x,
                                              u16* __restrict__ xh,
                                              u16* __restrict__ xl) {
    int b = blockIdx.z, c0 = blockIdx.y * 32, n0 = blockIdx.x * 32;
    __shared__ float tile[32][33];
    int t = threadIdx.x;
    int r = t >> 3, cg = (t & 7) * 4;
    if (n0 + cg + 3 < HW) {
        float4 v = *(const float4*)(x + (size_t)(b * INC + c0 + r) * HW + n0 + cg);
        tile[r][cg + 0] = v.x; tile[r][cg + 1] = v.y;
        tile[r][cg + 2] = v.z; tile[r][cg + 3] = v.w;
    }
    __syncthreads();
    int rn = t >> 3, cg2 = (t & 7) * 4;
    int n = n0 + rn;
    if (n < HW) {
        us4 h, l;
        split2(tile[cg2 + 0][rn], h.x, l.x);
        split2(tile[cg2 + 1][rn], h.y, l.y);
        split2(tile[cg2 + 2][rn], h.z, l.z);
        split2(tile[cg2 + 3][rn], h.w, l.w);
        size_t o = ((size_t)b * HW + n) * INC + c0 + cg2;
        *(us4*)(xh + o) = h;
        *(us4*)(xl + o) = l;
    }
}

// ---------------- u[b][m] = Wq_b[m] + Uq·s ---------------------------------
__global__ __launch_bounds__(256) void calc_u(const float* __restrict__ s,
                                              const float* __restrict__ Uq_w,
                                              const float* __restrict__ Wq_b,
                                              float* __restrict__ u) {
    __shared__ float ssh[SC];
    int b = blockIdx.x, m = threadIdx.x;
    ssh[m] = s[b * SC + m];
    __syncthreads();
    float acc = Wq_b[m];
    const float* uq = Uq_w + (size_t)m * SC;
    #pragma unroll 8
    for (int i = 0; i < SC; ++i) acc += ssh[i] * uq[i];
    u[b * MIDC + m] = acc;
}

// ---------------- GEMM1 (MFMA, split-3): sig_t[b][n][m] = stanh(Wq·X + u) --
// C[m=256, n=784] per b; BM=BN=128, BK=32; A=Wq[m][k], B=xt[n][k].
__global__ __launch_bounds__(256) void gemm1_mfma(
    const u16* __restrict__ aH, const u16* __restrict__ aL,
    const u16* __restrict__ bHp, const u16* __restrict__ bLp,
    const float* __restrict__ u,
    u16* __restrict__ sH, u16* __restrict__ sL) {
    const int b  = blockIdx.z;
    const int N0 = blockIdx.x * 128;
    const int M0 = blockIdx.y * 128;
    __shared__ short Asm[2][128][40];
    __shared__ short Bsm[2][128][40];
    const int t = threadIdx.x;
    const int lane = t & 63, w = t >> 6;
    const int wm = (w >> 1) * 64, wn = (w & 1) * 64;
    const int ln = lane & 15, kg = lane >> 4;

    const u16* bH = bHp + (size_t)b * HW * INC;
    const u16* bL = bLp + (size_t)b * HW * INC;

    const f4 zero = {0.f, 0.f, 0.f, 0.f};
    f4 acc[4][4];
    #pragma unroll
    for (int i = 0; i < 4; ++i)
        #pragma unroll
        for (int j = 0; j < 4; ++j) acc[i][j] = zero;

    for (int k0 = 0; k0 < INC; k0 += 32) {
        #pragma unroll
        for (int it = 0; it < 2; ++it) {
            int chunk = t + it * 256;          // 512 chunks of 8 bf16 per tile half
            int rl = chunk >> 2, kl = (chunk & 3) << 3;
            *(bfrag*)&Asm[0][rl][kl] = *(const bfrag*)(aH + (size_t)(M0 + rl) * INC + k0 + kl);
            *(bfrag*)&Asm[1][rl][kl] = *(const bfrag*)(aL + (size_t)(M0 + rl) * INC + k0 + kl);
            int ns = N0 + rl; ns = ns < HW ? ns : (HW - 1);   // clamp ragged n-tile
            *(bfrag*)&Bsm[0][rl][kl] = *(const bfrag*)(bH + (size_t)ns * INC + k0 + kl);
            *(bfrag*)&Bsm[1][rl][kl] = *(const bfrag*)(bL + (size_t)ns * INC + k0 + kl);
        }
        __syncthreads();
        bfrag ah[4], al[4], bh[4], bl[4];
        #pragma unroll
        for (int i = 0; i < 4; ++i) {
            ah[i] = *(const bfrag*)&Asm[0][wm + i * 16 + ln][kg * 8];
            al[i] = *(const bfrag*)&Asm[1][wm + i * 16 + ln][kg * 8];
            bh[i] = *(const bfrag*)&Bsm[0][wn + i * 16 + ln][kg * 8];
            bl[i] = *(const bfrag*)&Bsm[1][wn + i * 16 + ln][kg * 8];
        }
        #pragma unroll
        for (int mi = 0; mi < 4; ++mi)
            #pragma unroll
            for (int ni = 0; ni < 4; ++ni) {
                acc[mi][ni] = __builtin_amdgcn_mfma_f32_16x16x32_bf16(ah[mi], bh[ni], acc[mi][ni], 0, 0, 0);
                acc[mi][ni] = __builtin_amdgcn_mfma_f32_16x16x32_bf16(ah[mi], bl[ni], acc[mi][ni], 0, 0, 0);
                acc[mi][ni] = __builtin_amdgcn_mfma_f32_16x16x32_bf16(al[mi], bh[ni], acc[mi][ni], 0, 0, 0);
            }
        __syncthreads();
    }
    const float* ub = u + b * MIDC;
    #pragma unroll
    for (int ni = 0; ni < 4; ++ni) {
        int n = N0 + wn + ni * 16 + ln;
        if (n >= HW) continue;
        #pragma unroll
        for (int mi = 0; mi < 4; ++mi) {
            int mb = M0 + wm + mi * 16 + kg * 4;
            u16 hs[4], ls[4];
            #pragma unroll
            for (int r = 0; r < 4; ++r) {
                float p = acc[mi][ni][r] + ub[mb + r];
                float sg = 1.7159f * tanhf(0.66666667f * p);
                split2(sg, hs[r], ls[r]);
            }
            us4 vh = {hs[0], hs[1], hs[2], hs[3]};
            us4 vl = {ls[0], ls[1], ls[2], ls[3]};
            size_t o = ((size_t)b * HW + n) * MIDC + mb;
            *(us4*)(sH + o) = vh;
            *(us4*)(sL + o) = vl;
        }
    }
}

// ---------------- GEMM2 (MFMA, split-3): alpha[b][c][n] = Ww·sig + wb ------
// C[c=1024, n=784] per b; A=Ww[c][m], B=sig_t[n][m]; K=256.
__global__ __launch_bounds__(256) void gemm2_mfma(
    const u16* __restrict__ aH, const u16* __restrict__ aL,
    const u16* __restrict__ bHp, const u16* __restrict__ bLp,
    const float* __restrict__ wb,
    float* __restrict__ aout) {
    const int b  = blockIdx.z;
    const int N0 = blockIdx.x * 128;
    const int C0 = blockIdx.y * 128;
    __shared__ short Asm[2][128][40];
    __shared__ short Bsm[2][128][40];
    const int t = threadIdx.x;
    const int lane = t & 63, w = t >> 6;
    const int wm = (w >> 1) * 64, wn = (w & 1) * 64;
    const int ln = lane & 15, kg = lane >> 4;

    const u16* bH = bHp + (size_t)b * HW * MIDC;
    const u16* bL = bLp + (size_t)b * HW * MIDC;

    const f4 zero = {0.f, 0.f, 0.f, 0.f};
    f4 acc[4][4];
    #pragma unroll
    for (int i = 0; i < 4; ++i)
        #pragma unroll
        for (int j = 0; j < 4; ++j) acc[i][j] = zero;

    for (int k0 = 0; k0 < MIDC; k0 += 32) {
        #pragma unroll
        for (int it = 0; it < 2; ++it) {
            int chunk = t + it * 256;
            int rl = chunk >> 2, kl = (chunk & 3) << 3;
            *(bfrag*)&Asm[0][rl][kl] = *(const bfrag*)(aH + (size_t)(C0 + rl) * MIDC + k0 + kl);
            *(bfrag*)&Asm[1][rl][kl] = *(const bfrag*)(aL + (size_t)(C0 + rl) * MIDC + k0 + kl);
            int ns = N0 + rl; ns = ns < HW ? ns : (HW - 1);
            *(bfrag*)&Bsm[0][rl][kl] = *(const bfrag*)(bH + (size_t)ns * MIDC + k0 + kl);
            *(bfrag*)&Bsm[1][rl][kl] = *(const bfrag*)(bL + (size_t)ns * MIDC + k0 + kl);
        }
        __syncthreads();
        bfrag ah[4], al[4], bh[4], bl[4];
        #pragma unroll
        for (int i = 0; i < 4; ++i) {
            ah[i] = *(const bfrag*)&Asm[0][wm + i * 16 + ln][kg * 8];
            al[i] = *(const bfrag*)&Asm[1][wm + i * 16 + ln][kg * 8];
            bh[i] = *(const bfrag*)&Bsm[0][wn + i * 16 + ln][kg * 8];
            bl[i] = *(const bfrag*)&Bsm[1][wn + i * 16 + ln][kg * 8];
        }
        #pragma unroll
        for (int mi = 0; mi < 4; ++mi)
            #pragma unroll
            for (int ni = 0; ni < 4; ++ni) {
                acc[mi][ni] = __builtin_amdgcn_mfma_f32_16x16x32_bf16(ah[mi], bh[ni], acc[mi][ni], 0, 0, 0);
                acc[mi][ni] = __builtin_amdgcn_mfma_f32_16x16x32_bf16(ah[mi], bl[ni], acc[mi][ni], 0, 0, 0);
                acc[mi][ni] = __builtin_amdgcn_mfma_f32_16x16x32_bf16(al[mi], bh[ni], acc[mi][ni], 0, 0, 0);
            }
        __syncthreads();
    }
    #pragma unroll
    for (int ni = 0; ni < 4; ++ni) {
        int n = N0 + wn + ni * 16 + ln;
        if (n >= HW) continue;
        #pragma unroll
        for (int mi = 0; mi < 4; ++mi) {
            int cb = C0 + wm + mi * 16 + kg * 4;
            #pragma unroll
            for (int r = 0; r < 4; ++r) {
                float v = acc[mi][ni][r] + wb[cb + r];
                aout[((size_t)b * INC + cb + r) * HW + n] = v;
            }
        }
    }
}

// ---------------- per-(b,c) row: exact radix-select -> masked softmax -> dot
__global__ __launch_bounds__(256) void topk_softmax_reduce(const float* __restrict__ x,
                                                           float* __restrict__ out) {
    const int wid  = threadIdx.x >> 6;
    const int lane = threadIdx.x & 63;
    const int row  = blockIdx.x * 4 + wid;
    float* arow = out + BATCH * INC + (size_t)row * HW;
    const float* xrow = x + (size_t)row * HW;

    __shared__ int hist[4][256];

    float    v[NV];
    uint32_t key[NV];
    #pragma unroll
    for (int i = 0; i < NV; ++i) {
        int n = lane + 64 * i;
        bool ok = (n < HW);
        float f = ok ? arow[n] : 0.0f;
        v[i] = f;
        uint32_t uu = __float_as_uint(f);
        uint32_t k = (uu & 0x80000000u) ? ~uu : (uu | 0x80000000u);
        key[i] = ok ? k : 0u;
    }

    int kk = KSEL;
    uint32_t prefix = 0;
    #pragma unroll
    for (int round = 0; round < 4; ++round) {
        const int shift = 24 - 8 * round;
        const uint32_t himask = (round == 0) ? 0u : (0xFFFFFFFFu << (shift + 8));

        #pragma unroll
        for (int j = 0; j < 4; ++j) hist[wid][lane + 64 * j] = 0;
        __syncthreads();

        #pragma unroll
        for (int i = 0; i < NV; ++i) {
            if ((key[i] & himask) == prefix)
                atomicAdd(&hist[wid][(key[i] >> shift) & 255], 1);
        }
        __syncthreads();

        int h0 = hist[wid][4 * lane + 0];
        int h1 = hist[wid][4 * lane + 1];
        int h2 = hist[wid][4 * lane + 2];
        int h3 = hist[wid][4 * lane + 3];
        int g  = h0 + h1 + h2 + h3;
        int suf = g;
        #pragma unroll
        for (int off = 1; off < 64; off <<= 1) {
            int o = __shfl_down(suf, off, 64);
            suf += (lane + off < 64) ? o : 0;
        }
        int ex = suf - g;
        int cgt3 = ex;
        int cgt2 = cgt3 + h3;
        int cgt1 = cgt2 + h2;
        int cgt0 = cgt1 + h1;
        int bsel = -1, cg = 0;
        if (cgt0 < kk && kk <= cgt0 + h0) { bsel = 4 * lane + 0; cg = cgt0; }
        if (cgt1 < kk && kk <= cgt1 + h1) { bsel = 4 * lane + 1; cg = cgt1; }
        if (cgt2 < kk && kk <= cgt2 + h2) { bsel = 4 * lane + 2; cg = cgt2; }
        if (cgt3 < kk && kk <= cgt3 + h3) { bsel = 4 * lane + 3; cg = cgt3; }
        unsigned long long m = __ballot(bsel >= 0);
        int src = (int)__ffsll((long long)m) - 1;
        bsel = __shfl(bsel, src, 64);
        cg   = __shfl(cg,   src, 64);
        kk -= cg;
        prefix |= ((uint32_t)bsel) << shift;
        __syncthreads();
    }

    uint32_t tu = (prefix & 0x80000000u) ? (prefix ^ 0x80000000u) : ~prefix;
    const float th = __uint_as_float(tu);

    float mx = -INFINITY;
    #pragma unroll
    for (int i = 0; i < NV; ++i) {
        int n = lane + 64 * i;
        float f = v[i];
        f = (f < th) ? 0.0f : f;
        v[i] = f;
        if (n < HW) mx = fmaxf(mx, f);
    }
    #pragma unroll
    for (int off = 32; off; off >>= 1) mx = fmaxf(mx, __shfl_xor(mx, off, 64));

    float sum = 0.f;
    #pragma unroll
    for (int i = 0; i < NV; ++i) {
        int n = lane + 64 * i;
        float e = expf(v[i] - mx);
        v[i] = e;
        if (n < HW) sum += e;
    }
    #pragma unroll
    for (int off = 32; off; off >>= 1) sum += __shfl_xor(sum, off, 64);
    float inv = 1.0f / sum;

    float dot = 0.f;
    #pragma unroll
    for (int i = 0; i < NV; ++i) {
        int n = lane + 64 * i;
        if (n < HW) {
            float a = v[i] * inv;
            arow[n] = a;
            dot += xrow[n] * a;
        }
    }
    #pragma unroll
    for (int off = 32; off; off >>= 1) dot += __shfl_xor(dot, off, 64);
    if (lane == 0) out[row] = dot;
}

extern "C" void kernel_launch(void* const* d_in, const int* in_sizes, int n_in,
                              void* d_out, int out_size, void* d_ws, size_t ws_size,
                              hipStream_t stream) {
    const float* x    = (const float*)d_in[0];
    const float* s    = (const float*)d_in[1];
    const float* Wq_w = (const float*)d_in[2];
    const float* Wq_b = (const float*)d_in[3];
    const float* Uq_w = (const float*)d_in[4];
    const float* w_w  = (const float*)d_in[5];
    const float* w_b  = (const float*)d_in[6];
    float* out = (float*)d_out;

    // workspace layout (ushort counts)
    u16* xt_hi  = (u16*)d_ws;                                   // [32][784][1024]
    u16* sig_hi = xt_hi + (size_t)BATCH * HW * INC;             // [32][784][256]
    u16* sig_lo = sig_hi + (size_t)BATCH * HW * MIDC;
    u16* wq_hi  = sig_lo + (size_t)BATCH * HW * MIDC;           // [256][1024]
    u16* wq_lo  = wq_hi + MIDC * INC;
    u16* ww_hi  = wq_lo + MIDC * INC;                           // [1024][256]
    u16* ww_lo  = ww_hi + INC * MIDC;
    float* u    = (float*)(ww_lo + INC * MIDC);                 // [32][256]
    // xt_lo lives in the (currently dead) atten region of d_out
    u16* xt_lo  = (u16*)(out + BATCH * INC);                    // [32][784][1024]
    float* alpha = out + BATCH * INC;

    split_pairs<<<256, 256, 0, stream>>>(Wq_w, wq_hi, wq_lo, MIDC * INC / 4);
    split_pairs<<<256, 256, 0, stream>>>(w_w, ww_hi, ww_lo, INC * MIDC / 4);
    prep_x<<<dim3(25, 32, 32), 256, 0, stream>>>(x, xt_hi, xt_lo);
    calc_u<<<BATCH, 256, 0, stream>>>(s, Uq_w, Wq_b, u);
    gemm1_mfma<<<dim3(7, 2, 32), 256, 0, stream>>>(wq_hi, wq_lo, xt_hi, xt_lo, u, sig_hi, sig_lo);
    gemm2_mfma<<<dim3(7, 8, 32), 256, 0, stream>>>(ww_hi, ww_lo, sig_hi, sig_lo, w_b, alpha);
    topk_softmax_reduce<<<BATCH * INC / 4, 256, 0, stream>>>(x, out);
}

// Round 4
// 270.321 us; speedup vs baseline: 4.0138x; 1.0312x over previous
//
#include <hip/hip_runtime.h>
#include <hip/hip_bf16.h>
#include <math.h>

#define BATCH 32
#define INC 1024
#define MIDC 256
#define SC 256
#define HW 784
#define ROWS 25088   // BATCH*HW
#define KSEL 196     // int(0.25 * 784)
#define NV 13        // ceil(784/64)

typedef unsigned short u16;
typedef __attribute__((ext_vector_type(8))) short bfrag;   // 8 bf16 (4 VGPRs)
typedef __attribute__((ext_vector_type(4))) float f4;      // 4 fp32 acc

struct alignas(8) us4 { u16 x, y, z, w; };

__device__ inline u16 bf16_rn(float f) {
    uint32_t u = __float_as_uint(f);
    u += 0x7FFFu + ((u >> 16) & 1u);
    return (u16)(u >> 16);
}
__device__ inline void split2(float f, u16& hi, u16& lo) {
    u16 h = bf16_rn(f);
    float fh = __uint_as_float(((uint32_t)h) << 16);
    hi = h;
    lo = bf16_rn(f - fh);
}
__device__ inline float stanh_fast(float p) {
    // 1.7159*tanh(2p/3) = 1.7159*(1 - 2/(exp(4p/3)+1))
    float e = __expf(1.33333333f * p);
    return 1.7159f * (1.0f - 2.0f / (e + 1.0f));
}

// ---------------- split fp32 weights into bf16 hi/lo (layout preserved) ----
__global__ __launch_bounds__(256) void split_pairs(const float* __restrict__ src,
                                                   u16* __restrict__ hi,
                                                   u16* __restrict__ lo, int n4) {
    int i = blockIdx.x * 256 + threadIdx.x;
    if (i >= n4) return;
    float4 v = ((const float4*)src)[i];
    us4 h, l;
    split2(v.x, h.x, l.x); split2(v.y, h.y, l.y);
    split2(v.z, h.z, l.z); split2(v.w, h.w, l.w);
    ((us4*)hi)[i] = h; ((us4*)lo)[i] = l;
}

// ---------------- transpose x[b][c][n] -> xt[b][n][c] as bf16 hi/lo --------
__global__ __launch_bounds__(256) void prep_x(const float* __restrict__ x,
                                              u16* __restrict__ xh,
                                              u16* __restrict__ xl) {
    int b = blockIdx.z, c0 = blockIdx.y * 32, n0 = blockIdx.x * 32;
    __shared__ float tile[32][33];
    int t = threadIdx.x;
    int r = t >> 3, cg = (t & 7) * 4;
    if (n0 + cg + 3 < HW) {
        float4 v = *(const float4*)(x + (size_t)(b * INC + c0 + r) * HW + n0 + cg);
        tile[r][cg + 0] = v.x; tile[r][cg + 1] = v.y;
        tile[r][cg + 2] = v.z; tile[r][cg + 3] = v.w;
    }
    __syncthreads();
    int rn = t >> 3, cg2 = (t & 7) * 4;
    int n = n0 + rn;
    if (n < HW) {
        us4 h, l;
        split2(tile[cg2 + 0][rn], h.x, l.x);
        split2(tile[cg2 + 1][rn], h.y, l.y);
        split2(tile[cg2 + 2][rn], h.z, l.z);
        split2(tile[cg2 + 3][rn], h.w, l.w);
        size_t o = ((size_t)b * HW + n) * INC + c0 + cg2;
        *(us4*)(xh + o) = h;
        *(us4*)(xl + o) = l;
    }
}

// ---------------- u[b][m] = Wq_b[m] + Uq·s ---------------------------------
__global__ __launch_bounds__(256) void calc_u(const float* __restrict__ s,
                                              const float* __restrict__ Uq_w,
                                              const float* __restrict__ Wq_b,
                                              float* __restrict__ u) {
    __shared__ float ssh[SC];
    int b = blockIdx.x, m = threadIdx.x;
    ssh[m] = s[b * SC + m];
    __syncthreads();
    float acc = Wq_b[m];
    const float* uq = Uq_w + (size_t)m * SC;
    #pragma unroll 8
    for (int i = 0; i < SC; ++i) acc += ssh[i] * uq[i];
    u[b * MIDC + m] = acc;
}

// ---------------- GEMM1: sig_t[R][m] = stanh(Wq·xt[R] + u[R/784][m]) -------
// Flattened: M=25088 rows (R), N=256 (mid). BM=64 rows x BN=128 mid. K=1024.
__global__ __launch_bounds__(256) void gemm1_mfma(
    const u16* __restrict__ aH, const u16* __restrict__ aL,   // Wq [256][1024]
    const u16* __restrict__ bH, const u16* __restrict__ bL,   // xt [25088][1024]
    const float* __restrict__ u,
    u16* __restrict__ sH, u16* __restrict__ sL) {             // sig [25088][256]
    const int R0 = blockIdx.x * 64;
    const int M0 = blockIdx.y * 128;
    __shared__ short Asm[2][128][40];
    __shared__ short Bsm[2][64][40];
    const int t = threadIdx.x;
    const int lane = t & 63, w = t >> 6;
    const int wc = (w >> 1) * 64;      // mid offset within 128
    const int wr = (w & 1) * 32;       // row offset within 64
    const int ln = lane & 15, kg = lane >> 4;

    // staging chunk coords (8 bf16 per chunk)
    const int ar0 = t >> 2, ar1 = (t >> 2) + 64;
    const int akc = (t & 3) * 8;
    const size_t aoff0 = (size_t)(M0 + ar0) * INC + akc;
    const size_t aoff1 = (size_t)(M0 + ar1) * INC + akc;
    const size_t boff  = (size_t)(R0 + ar0) * INC + akc;   // rows 0..63

    f4 acc[4][2];
    const f4 zero = {0.f, 0.f, 0.f, 0.f};
    #pragma unroll
    for (int i = 0; i < 4; ++i) { acc[i][0] = zero; acc[i][1] = zero; }

    bfrag rAh0, rAh1, rAl0, rAl1, rBh, rBl;
    #define G1_LOAD(K0)                                              \
        rAh0 = *(const bfrag*)(aH + aoff0 + (K0));                   \
        rAh1 = *(const bfrag*)(aH + aoff1 + (K0));                   \
        rAl0 = *(const bfrag*)(aL + aoff0 + (K0));                   \
        rAl1 = *(const bfrag*)(aL + aoff1 + (K0));                   \
        rBh  = *(const bfrag*)(bH + boff  + (K0));                   \
        rBl  = *(const bfrag*)(bL + boff  + (K0));

    G1_LOAD(0)
    for (int k0 = 0; k0 < INC; k0 += 32) {
        *(bfrag*)&Asm[0][ar0][akc] = rAh0;
        *(bfrag*)&Asm[0][ar1][akc] = rAh1;
        *(bfrag*)&Asm[1][ar0][akc] = rAl0;
        *(bfrag*)&Asm[1][ar1][akc] = rAl1;
        *(bfrag*)&Bsm[0][ar0][akc] = rBh;
        *(bfrag*)&Bsm[1][ar0][akc] = rBl;
        __syncthreads();
        if (k0 + 32 < INC) { G1_LOAD(k0 + 32) }
        bfrag bh0 = *(const bfrag*)&Bsm[0][wr + ln][kg * 8];
        bfrag bh1 = *(const bfrag*)&Bsm[0][wr + 16 + ln][kg * 8];
        bfrag bl0 = *(const bfrag*)&Bsm[1][wr + ln][kg * 8];
        bfrag bl1 = *(const bfrag*)&Bsm[1][wr + 16 + ln][kg * 8];
        #pragma unroll
        for (int mi = 0; mi < 4; ++mi) {
            bfrag ah = *(const bfrag*)&Asm[0][wc + mi * 16 + ln][kg * 8];
            bfrag al = *(const bfrag*)&Asm[1][wc + mi * 16 + ln][kg * 8];
            acc[mi][0] = __builtin_amdgcn_mfma_f32_16x16x32_bf16(ah, bh0, acc[mi][0], 0, 0, 0);
            acc[mi][0] = __builtin_amdgcn_mfma_f32_16x16x32_bf16(ah, bl0, acc[mi][0], 0, 0, 0);
            acc[mi][0] = __builtin_amdgcn_mfma_f32_16x16x32_bf16(al, bh0, acc[mi][0], 0, 0, 0);
            acc[mi][1] = __builtin_amdgcn_mfma_f32_16x16x32_bf16(ah, bh1, acc[mi][1], 0, 0, 0);
            acc[mi][1] = __builtin_amdgcn_mfma_f32_16x16x32_bf16(ah, bl1, acc[mi][1], 0, 0, 0);
            acc[mi][1] = __builtin_amdgcn_mfma_f32_16x16x32_bf16(al, bh1, acc[mi][1], 0, 0, 0);
        }
        __syncthreads();
    }
    #undef G1_LOAD

    #pragma unroll
    for (int ni = 0; ni < 2; ++ni) {
        int R = R0 + wr + ni * 16 + ln;
        int b = R / HW;
        #pragma unroll
        for (int mi = 0; mi < 4; ++mi) {
            int mb = M0 + wc + mi * 16 + kg * 4;
            float uv[4];
            *(float4*)uv = *(const float4*)(u + b * MIDC + mb);
            u16 hs[4], ls[4];
            #pragma unroll
            for (int r = 0; r < 4; ++r) {
                float sg = stanh_fast(acc[mi][ni][r] + uv[r]);
                split2(sg, hs[r], ls[r]);
            }
            us4 vh = {hs[0], hs[1], hs[2], hs[3]};
            us4 vl = {ls[0], ls[1], ls[2], ls[3]};
            size_t o = (size_t)R * MIDC + mb;
            *(us4*)(sH + o) = vh;
            *(us4*)(sL + o) = vl;
        }
    }
}

// ---------------- GEMM2: alpha[b][c][n] = Ww·sig_t[R] + wb, R=(b,n) --------
// Flattened: 128 c x 128 rows per block. K=256.
__global__ __launch_bounds__(256) void gemm2_mfma(
    const u16* __restrict__ aH, const u16* __restrict__ aL,   // Ww [1024][256]
    const u16* __restrict__ bH, const u16* __restrict__ bL,   // sig [25088][256]
    const float* __restrict__ wb,
    float* __restrict__ aout) {
    const int R0 = blockIdx.x * 128;
    const int C0 = blockIdx.y * 128;
    __shared__ short Asm[2][128][40];
    __shared__ short Bsm[2][128][40];
    const int t = threadIdx.x;
    const int lane = t & 63, w = t >> 6;
    const int wc = (w >> 1) * 64;      // c offset
    const int wr = (w & 1) * 64;       // row offset
    const int ln = lane & 15, kg = lane >> 4;

    const int r0 = t >> 2, r1 = (t >> 2) + 64;
    const int kc = (t & 3) * 8;
    const size_t aoff0 = (size_t)(C0 + r0) * MIDC + kc;
    const size_t aoff1 = (size_t)(C0 + r1) * MIDC + kc;
    const size_t boff0 = (size_t)(R0 + r0) * MIDC + kc;
    const size_t boff1 = (size_t)(R0 + r1) * MIDC + kc;

    f4 acc[4][4];
    const f4 zero = {0.f, 0.f, 0.f, 0.f};
    #pragma unroll
    for (int i = 0; i < 4; ++i)
        #pragma unroll
        for (int j = 0; j < 4; ++j) acc[i][j] = zero;

    bfrag rAh0, rAh1, rAl0, rAl1, rBh0, rBh1, rBl0, rBl1;
    #define G2_LOAD(K0)                                              \
        rAh0 = *(const bfrag*)(aH + aoff0 + (K0));                   \
        rAh1 = *(const bfrag*)(aH + aoff1 + (K0));                   \
        rAl0 = *(const bfrag*)(aL + aoff0 + (K0));                   \
        rAl1 = *(const bfrag*)(aL + aoff1 + (K0));                   \
        rBh0 = *(const bfrag*)(bH + boff0 + (K0));                   \
        rBh1 = *(const bfrag*)(bH + boff1 + (K0));                   \
        rBl0 = *(const bfrag*)(bL + boff0 + (K0));                   \
        rBl1 = *(const bfrag*)(bL + boff1 + (K0));

    G2_LOAD(0)
    for (int k0 = 0; k0 < MIDC; k0 += 32) {
        *(bfrag*)&Asm[0][r0][kc] = rAh0;
        *(bfrag*)&Asm[0][r1][kc] = rAh1;
        *(bfrag*)&Asm[1][r0][kc] = rAl0;
        *(bfrag*)&Asm[1][r1][kc] = rAl1;
        *(bfrag*)&Bsm[0][r0][kc] = rBh0;
        *(bfrag*)&Bsm[0][r1][kc] = rBh1;
        *(bfrag*)&Bsm[1][r0][kc] = rBl0;
        *(bfrag*)&Bsm[1][r1][kc] = rBl1;
        __syncthreads();
        if (k0 + 32 < MIDC) { G2_LOAD(k0 + 32) }
        bfrag bh[4], bl[4];
        #pragma unroll
        for (int ni = 0; ni < 4; ++ni) {
            bh[ni] = *(const bfrag*)&Bsm[0][wr + ni * 16 + ln][kg * 8];
            bl[ni] = *(const bfrag*)&Bsm[1][wr + ni * 16 + ln][kg * 8];
        }
        #pragma unroll
        for (int mi = 0; mi < 4; ++mi) {
            bfrag ah = *(const bfrag*)&Asm[0][wc + mi * 16 + ln][kg * 8];
            bfrag al = *(const bfrag*)&Asm[1][wc + mi * 16 + ln][kg * 8];
            #pragma unroll
            for (int ni = 0; ni < 4; ++ni) {
                acc[mi][ni] = __builtin_amdgcn_mfma_f32_16x16x32_bf16(ah, bh[ni], acc[mi][ni], 0, 0, 0);
                acc[mi][ni] = __builtin_amdgcn_mfma_f32_16x16x32_bf16(ah, bl[ni], acc[mi][ni], 0, 0, 0);
                acc[mi][ni] = __builtin_amdgcn_mfma_f32_16x16x32_bf16(al, bh[ni], acc[mi][ni], 0, 0, 0);
            }
        }
        __syncthreads();
    }
    #undef G2_LOAD

    #pragma unroll
    for (int ni = 0; ni < 4; ++ni) {
        int R = R0 + wr + ni * 16 + ln;
        int b = R / HW;
        int n = R - b * HW;
        float* arow = aout + (size_t)b * INC * HW + n;
        #pragma unroll
        for (int mi = 0; mi < 4; ++mi) {
            int cb = C0 + wc + mi * 16 + kg * 4;
            float wv[4];
            *(float4*)wv = *(const float4*)(wb + cb);
            #pragma unroll
            for (int r = 0; r < 4; ++r)
                arow[(size_t)(cb + r) * HW] = acc[mi][ni][r] + wv[r];
        }
    }
}

// ---------------- per-(b,c) row: exact radix-select -> masked softmax -> dot
__global__ __launch_bounds__(256) void topk_softmax_reduce(const float* __restrict__ x,
                                                           float* __restrict__ out) {
    const int wid  = threadIdx.x >> 6;
    const int lane = threadIdx.x & 63;
    const int row  = blockIdx.x * 4 + wid;
    float* arow = out + BATCH * INC + (size_t)row * HW;
    const float* xrow = x + (size_t)row * HW;

    __shared__ int hist[4][4][256];   // [wave][subgroup][bin]
    int* hp = &hist[wid][0][0];
    const int g = lane >> 4;          // quarter-wave subgroup

    float    v[NV];
    uint32_t key[NV];
    #pragma unroll
    for (int i = 0; i < NV; ++i) {
        int n = lane + 64 * i;
        bool ok = (n < HW);
        float f = ok ? arow[n] : 0.0f;
        v[i] = f;
        uint32_t uu = __float_as_uint(f);
        uint32_t k = (uu & 0x80000000u) ? ~uu : (uu | 0x80000000u);
        key[i] = ok ? k : 0u;
    }

    int kk = KSEL;
    uint32_t prefix = 0;

    // ---- round 0 (bits 31:24): exponent-clustered -> 4 sub-histograms ----
    {
        const int4 z4 = {0, 0, 0, 0};
        #pragma unroll
        for (int j = 0; j < 4; ++j) *(int4*)&hp[4 * lane + 256 * j] = z4;
        __syncthreads();
        #pragma unroll
        for (int i = 0; i < NV; ++i)
            atomicAdd(&hist[wid][g][key[i] >> 24], 1);
        __syncthreads();
        int4 c0 = *(const int4*)&hist[wid][0][4 * lane];
        int4 c1 = *(const int4*)&hist[wid][1][4 * lane];
        int4 c2 = *(const int4*)&hist[wid][2][4 * lane];
        int4 c3 = *(const int4*)&hist[wid][3][4 * lane];
        int h0 = c0.x + c1.x + c2.x + c3.x;
        int h1 = c0.y + c1.y + c2.y + c3.y;
        int h2 = c0.z + c1.z + c2.z + c3.z;
        int h3 = c0.w + c1.w + c2.w + c3.w;
        int gsum = h0 + h1 + h2 + h3;
        int suf = gsum;
        #pragma unroll
        for (int off = 1; off < 64; off <<= 1) {
            int o = __shfl_down(suf, off, 64);
            suf += (lane + off < 64) ? o : 0;
        }
        int ex = suf - gsum;
        int cgt3 = ex, cgt2 = cgt3 + h3, cgt1 = cgt2 + h2, cgt0 = cgt1 + h1;
        int bsel = -1, cg = 0;
        if (cgt0 < kk && kk <= cgt0 + h0) { bsel = 4 * lane + 0; cg = cgt0; }
        if (cgt1 < kk && kk <= cgt1 + h1) { bsel = 4 * lane + 1; cg = cgt1; }
        if (cgt2 < kk && kk <= cgt2 + h2) { bsel = 4 * lane + 2; cg = cgt2; }
        if (cgt3 < kk && kk <= cgt3 + h3) { bsel = 4 * lane + 3; cg = cgt3; }
        unsigned long long m = __ballot(bsel >= 0);
        int src = (int)__ffsll((long long)m) - 1;
        bsel = __shfl(bsel, src, 64);
        cg   = __shfl(cg,   src, 64);
        kk -= cg;
        prefix = ((uint32_t)bsel) << 24;
        __syncthreads();
    }

    // ---- rounds 1..3: mantissa bits, uniform -> single histogram ---------
    #pragma unroll
    for (int round = 1; round < 4; ++round) {
        const int shift = 24 - 8 * round;
        const uint32_t himask = 0xFFFFFFFFu << (shift + 8);
        const int4 z4 = {0, 0, 0, 0};
        *(int4*)&hp[4 * lane] = z4;
        __syncthreads();
        #pragma unroll
        for (int i = 0; i < NV; ++i) {
            if ((key[i] & himask) == prefix)
                atomicAdd(&hp[(key[i] >> shift) & 255], 1);
        }
        __syncthreads();
        int4 c = *(const int4*)&hp[4 * lane];
        int h0 = c.x, h1 = c.y, h2 = c.z, h3 = c.w;
        int gsum = h0 + h1 + h2 + h3;
        int suf = gsum;
        #pragma unroll
        for (int off = 1; off < 64; off <<= 1) {
            int o = __shfl_down(suf, off, 64);
            suf += (lane + off < 64) ? o : 0;
        }
        int ex = suf - gsum;
        int cgt3 = ex, cgt2 = cgt3 + h3, cgt1 = cgt2 + h2, cgt0 = cgt1 + h1;
        int bsel = -1, cg = 0;
        if (cgt0 < kk && kk <= cgt0 + h0) { bsel = 4 * lane + 0; cg = cgt0; }
        if (cgt1 < kk && kk <= cgt1 + h1) { bsel = 4 * lane + 1; cg = cgt1; }
        if (cgt2 < kk && kk <= cgt2 + h2) { bsel = 4 * lane + 2; cg = cgt2; }
        if (cgt3 < kk && kk <= cgt3 + h3) { bsel = 4 * lane + 3; cg = cgt3; }
        unsigned long long m = __ballot(bsel >= 0);
        int src = (int)__ffsll((long long)m) - 1;
        bsel = __shfl(bsel, src, 64);
        cg   = __shfl(cg,   src, 64);
        kk -= cg;
        prefix |= ((uint32_t)bsel) << shift;
        __syncthreads();
    }

    uint32_t tu = (prefix & 0x80000000u) ? (prefix ^ 0x80000000u) : ~prefix;
    const float th = __uint_as_float(tu);

    float mx = -INFINITY;
    #pragma unroll
    for (int i = 0; i < NV; ++i) {
        int n = lane + 64 * i;
        float f = v[i];
        f = (f < th) ? 0.0f : f;
        v[i] = f;
        if (n < HW) mx = fmaxf(mx, f);
    }
    #pragma unroll
    for (int off = 32; off; off >>= 1) mx = fmaxf(mx, __shfl_xor(mx, off, 64));

    float sum = 0.f;
    #pragma unroll
    for (int i = 0; i < NV; ++i) {
        int n = lane + 64 * i;
        float e = __expf(v[i] - mx);
        v[i] = e;
        if (n < HW) sum += e;
    }
    #pragma unroll
    for (int off = 32; off; off >>= 1) sum += __shfl_xor(sum, off, 64);
    float inv = 1.0f / sum;

    float dot = 0.f;
    #pragma unroll
    for (int i = 0; i < NV; ++i) {
        int n = lane + 64 * i;
        if (n < HW) {
            float a = v[i] * inv;
            arow[n] = a;
            dot += xrow[n] * a;
        }
    }
    #pragma unroll
    for (int off = 32; off; off >>= 1) dot += __shfl_xor(dot, off, 64);
    if (lane == 0) out[row] = dot;
}

extern "C" void kernel_launch(void* const* d_in, const int* in_sizes, int n_in,
                              void* d_out, int out_size, void* d_ws, size_t ws_size,
                              hipStream_t stream) {
    const float* x    = (const float*)d_in[0];
    const float* s    = (const float*)d_in[1];
    const float* Wq_w = (const float*)d_in[2];
    const float* Wq_b = (const float*)d_in[3];
    const float* Uq_w = (const float*)d_in[4];
    const float* w_w  = (const float*)d_in[5];
    const float* w_b  = (const float*)d_in[6];
    float* out = (float*)d_out;

    u16* xt_hi  = (u16*)d_ws;                                   // [25088][1024]
    u16* sig_hi = xt_hi + (size_t)ROWS * INC;                   // [25088][256]
    u16* sig_lo = sig_hi + (size_t)ROWS * MIDC;
    u16* wq_hi  = sig_lo + (size_t)ROWS * MIDC;                 // [256][1024]
    u16* wq_lo  = wq_hi + MIDC * INC;
    u16* ww_hi  = wq_lo + MIDC * INC;                           // [1024][256]
    u16* ww_lo  = ww_hi + INC * MIDC;
    float* u    = (float*)(ww_lo + INC * MIDC);                 // [32][256]
    u16* xt_lo  = (u16*)(out + BATCH * INC);                    // staged in atten slot
    float* alpha = out + BATCH * INC;

    split_pairs<<<256, 256, 0, stream>>>(Wq_w, wq_hi, wq_lo, MIDC * INC / 4);
    split_pairs<<<256, 256, 0, stream>>>(w_w, ww_hi, ww_lo, INC * MIDC / 4);
    prep_x<<<dim3(25, 32, 32), 256, 0, stream>>>(x, xt_hi, xt_lo);
    calc_u<<<BATCH, 256, 0, stream>>>(s, Uq_w, Wq_b, u);
    gemm1_mfma<<<dim3(ROWS / 64, 2), 256, 0, stream>>>(wq_hi, wq_lo, xt_hi, xt_lo, u, sig_hi, sig_lo);
    gemm2_mfma<<<dim3(ROWS / 128, 8), 256, 0, stream>>>(ww_hi, ww_lo, sig_hi, sig_lo, w_b, alpha);
    topk_softmax_reduce<<<BATCH * INC / 4, 256, 0, stream>>>(x, out);
}

// Round 5
// 184.272 us; speedup vs baseline: 5.8881x; 1.4670x over previous
//
#include <hip/hip_runtime.h>
#include <hip/hip_bf16.h>
#include <hip/hip_fp16.h>
#include <math.h>

#define BATCH 32
#define INC 1024
#define MIDC 256
#define SC 256
#define HW 784
#define ROWS 25088   // BATCH*HW
#define KSEL 196     // int(0.25 * 784)
#define NV 13        // ceil(784/64)

typedef _Float16 f16;
typedef __attribute__((ext_vector_type(8))) _Float16 hfrag;  // 8 fp16 (4 VGPRs)
typedef __attribute__((ext_vector_type(4))) float f4;        // 4 fp32 acc

struct alignas(8) h4s { f16 x, y, z, w; };

__device__ inline float stanh_fast(float p) {
    // 1.7159*tanh(2p/3) = 1.7159*(1 - 2/(exp(4p/3)+1))
    float e = __expf(1.33333333f * p);
    return 1.7159f * (1.0f - 2.0f / (e + 1.0f));
}

// ---------------- fp32 -> fp16 weight convert (layout preserved) -----------
__global__ __launch_bounds__(256) void cvt_f16(const float* __restrict__ src,
                                               f16* __restrict__ dst, int n4) {
    int i = blockIdx.x * 256 + threadIdx.x;
    if (i >= n4) return;
    float4 v = ((const float4*)src)[i];
    h4s h = { (f16)v.x, (f16)v.y, (f16)v.z, (f16)v.w };
    ((h4s*)dst)[i] = h;
}

// ---------------- transpose x[b][c][n] -> xt[b][n][c] as fp16 --------------
__global__ __launch_bounds__(256) void prep_x(const float* __restrict__ x,
                                              f16* __restrict__ xh) {
    int b = blockIdx.z, c0 = blockIdx.y * 32, n0 = blockIdx.x * 32;
    __shared__ float tile[32][33];
    int t = threadIdx.x;
    int r = t >> 3, cg = (t & 7) * 4;
    if (n0 + cg + 3 < HW) {
        float4 v = *(const float4*)(x + (size_t)(b * INC + c0 + r) * HW + n0 + cg);
        tile[r][cg + 0] = v.x; tile[r][cg + 1] = v.y;
        tile[r][cg + 2] = v.z; tile[r][cg + 3] = v.w;
    }
    __syncthreads();
    int rn = t >> 3, cg2 = (t & 7) * 4;
    int n = n0 + rn;
    if (n < HW) {
        h4s h = { (f16)tile[cg2 + 0][rn], (f16)tile[cg2 + 1][rn],
                  (f16)tile[cg2 + 2][rn], (f16)tile[cg2 + 3][rn] };
        *(h4s*)(xh + ((size_t)b * HW + n) * INC + c0 + cg2) = h;
    }
}

// ---------------- u[b][m] = Wq_b[m] + Uq·s ---------------------------------
__global__ __launch_bounds__(256) void calc_u(const float* __restrict__ s,
                                              const float* __restrict__ Uq_w,
                                              const float* __restrict__ Wq_b,
                                              float* __restrict__ u) {
    __shared__ float ssh[SC];
    int b = blockIdx.x, m = threadIdx.x;
    ssh[m] = s[b * SC + m];
    __syncthreads();
    float acc = Wq_b[m];
    const float* uq = Uq_w + (size_t)m * SC;
    #pragma unroll 8
    for (int i = 0; i < SC; ++i) acc += ssh[i] * uq[i];
    u[b * MIDC + m] = acc;
}

// ---------------- GEMM1: sig_t[R][m] = stanh(Wq·xt[R] + u[R/784][m]) -------
// M=25088 rows (R), N=256 (mid). BM=64 rows x BN=128 mid. K=1024. fp16 MFMA.
__global__ __launch_bounds__(256) void gemm1_mfma(
    const f16* __restrict__ A,   // Wq [256][1024]
    const f16* __restrict__ B,   // xt [25088][1024]
    const float* __restrict__ u,
    f16* __restrict__ S) {       // sig [25088][256]
    const int R0 = blockIdx.x * 64;
    const int M0 = blockIdx.y * 128;
    __shared__ f16 Asm[128][40];
    __shared__ f16 Bsm[64][40];
    const int t = threadIdx.x;
    const int lane = t & 63, w = t >> 6;
    const int wc = (w >> 1) * 64;      // mid offset within 128
    const int wr = (w & 1) * 32;       // row offset within 64
    const int ln = lane & 15, kg = lane >> 4;

    const int ar0 = t >> 2, ar1 = ar0 + 64;
    const int akc = (t & 3) * 8;
    const size_t aoff0 = (size_t)(M0 + ar0) * INC + akc;
    const size_t aoff1 = (size_t)(M0 + ar1) * INC + akc;
    const size_t boff  = (size_t)(R0 + ar0) * INC + akc;

    f4 acc[4][2];
    const f4 zero = {0.f, 0.f, 0.f, 0.f};
    #pragma unroll
    for (int i = 0; i < 4; ++i) { acc[i][0] = zero; acc[i][1] = zero; }

    hfrag rA0, rA1, rB;
    #define G1_LOAD(K0)                                   \
        rA0 = *(const hfrag*)(A + aoff0 + (K0));          \
        rA1 = *(const hfrag*)(A + aoff1 + (K0));          \
        rB  = *(const hfrag*)(B + boff  + (K0));

    G1_LOAD(0)
    for (int k0 = 0; k0 < INC; k0 += 32) {
        *(hfrag*)&Asm[ar0][akc] = rA0;
        *(hfrag*)&Asm[ar1][akc] = rA1;
        *(hfrag*)&Bsm[ar0][akc] = rB;
        __syncthreads();
        if (k0 + 32 < INC) { G1_LOAD(k0 + 32) }
        hfrag b0 = *(const hfrag*)&Bsm[wr + ln][kg * 8];
        hfrag b1 = *(const hfrag*)&Bsm[wr + 16 + ln][kg * 8];
        #pragma unroll
        for (int mi = 0; mi < 4; ++mi) {
            hfrag a = *(const hfrag*)&Asm[wc + mi * 16 + ln][kg * 8];
            acc[mi][0] = __builtin_amdgcn_mfma_f32_16x16x32_f16(a, b0, acc[mi][0], 0, 0, 0);
            acc[mi][1] = __builtin_amdgcn_mfma_f32_16x16x32_f16(a, b1, acc[mi][1], 0, 0, 0);
        }
        __syncthreads();
    }
    #undef G1_LOAD

    #pragma unroll
    for (int ni = 0; ni < 2; ++ni) {
        int R = R0 + wr + ni * 16 + ln;
        int b = R / HW;
        #pragma unroll
        for (int mi = 0; mi < 4; ++mi) {
            int mb = M0 + wc + mi * 16 + kg * 4;
            float uv[4];
            *(float4*)uv = *(const float4*)(u + b * MIDC + mb);
            h4s hv;
            hv.x = (f16)stanh_fast(acc[mi][ni][0] + uv[0]);
            hv.y = (f16)stanh_fast(acc[mi][ni][1] + uv[1]);
            hv.z = (f16)stanh_fast(acc[mi][ni][2] + uv[2]);
            hv.w = (f16)stanh_fast(acc[mi][ni][3] + uv[3]);
            *(h4s*)(S + (size_t)R * MIDC + mb) = hv;
        }
    }
}

// ---------------- GEMM2: alpha[b][c][n] = Ww·sig_t[R] + wb, R=(b,n) --------
// 128 c x 128 rows per block. K=256. fp16 MFMA.
__global__ __launch_bounds__(256) void gemm2_mfma(
    const f16* __restrict__ A,   // Ww [1024][256]
    const f16* __restrict__ B,   // sig [25088][256]
    const float* __restrict__ wb,
    float* __restrict__ aout) {
    const int R0 = blockIdx.x * 128;
    const int C0 = blockIdx.y * 128;
    __shared__ f16 Asm[128][40];
    __shared__ f16 Bsm[128][40];
    const int t = threadIdx.x;
    const int lane = t & 63, w = t >> 6;
    const int wc = (w >> 1) * 64;      // c offset
    const int wr = (w & 1) * 64;       // row offset
    const int ln = lane & 15, kg = lane >> 4;

    const int r0 = t >> 2, r1 = r0 + 64;
    const int kc = (t & 3) * 8;
    const size_t aoff0 = (size_t)(C0 + r0) * MIDC + kc;
    const size_t aoff1 = (size_t)(C0 + r1) * MIDC + kc;
    const size_t boff0 = (size_t)(R0 + r0) * MIDC + kc;
    const size_t boff1 = (size_t)(R0 + r1) * MIDC + kc;

    f4 acc[4][4];
    const f4 zero = {0.f, 0.f, 0.f, 0.f};
    #pragma unroll
    for (int i = 0; i < 4; ++i)
        #pragma unroll
        for (int j = 0; j < 4; ++j) acc[i][j] = zero;

    hfrag rA0, rA1, rB0, rB1;
    #define G2_LOAD(K0)                                   \
        rA0 = *(const hfrag*)(A + aoff0 + (K0));          \
        rA1 = *(const hfrag*)(A + aoff1 + (K0));          \
        rB0 = *(const hfrag*)(B + boff0 + (K0));          \
        rB1 = *(const hfrag*)(B + boff1 + (K0));

    G2_LOAD(0)
    for (int k0 = 0; k0 < MIDC; k0 += 32) {
        *(hfrag*)&Asm[r0][kc] = rA0;
        *(hfrag*)&Asm[r1][kc] = rA1;
        *(hfrag*)&Bsm[r0][kc] = rB0;
        *(hfrag*)&Bsm[r1][kc] = rB1;
        __syncthreads();
        if (k0 + 32 < MIDC) { G2_LOAD(k0 + 32) }
        hfrag bh[4];
        #pragma unroll
        for (int ni = 0; ni < 4; ++ni)
            bh[ni] = *(const hfrag*)&Bsm[wr + ni * 16 + ln][kg * 8];
        #pragma unroll
        for (int mi = 0; mi < 4; ++mi) {
            hfrag a = *(const hfrag*)&Asm[wc + mi * 16 + ln][kg * 8];
            #pragma unroll
            for (int ni = 0; ni < 4; ++ni)
                acc[mi][ni] = __builtin_amdgcn_mfma_f32_16x16x32_f16(a, bh[ni], acc[mi][ni], 0, 0, 0);
        }
        __syncthreads();
    }
    #undef G2_LOAD

    #pragma unroll
    for (int ni = 0; ni < 4; ++ni) {
        int R = R0 + wr + ni * 16 + ln;
        int b = R / HW;
        int n = R - b * HW;
        float* arow = aout + (size_t)b * INC * HW + n;
        #pragma unroll
        for (int mi = 0; mi < 4; ++mi) {
            int cb = C0 + wc + mi * 16 + kg * 4;
            float wv[4];
            *(float4*)wv = *(const float4*)(wb + cb);
            #pragma unroll
            for (int r = 0; r < 4; ++r)
                arow[(size_t)(cb + r) * HW] = acc[mi][ni][r] + wv[r];
        }
    }
}

// ---------------- per-(b,c) row: exact radix-select -> masked softmax -> dot
// Sub-histograms padded to 264 ints so subgroup g sits at bank offset 8g
// (264*4 B mod 128 B = 32 B) -- the R4 version's 256-int stride aliased all
// subgroups onto the same banks (conflict counter was unchanged).
__global__ __launch_bounds__(256) void topk_softmax_reduce(const float* __restrict__ x,
                                                           float* __restrict__ out) {
    const int wid  = threadIdx.x >> 6;
    const int lane = threadIdx.x & 63;
    const int row  = blockIdx.x * 4 + wid;
    float* arow = out + BATCH * INC + (size_t)row * HW;
    const float* xrow = x + (size_t)row * HW;

    __shared__ int hist[4][4][264];   // [wave][subgroup][bin(+pad)]
    int* hp0 = &hist[wid][0][0];
    const int g = lane >> 4;          // quarter-wave subgroup

    float    v[NV];
    uint32_t key[NV];
    #pragma unroll
    for (int i = 0; i < NV; ++i) {
        int n = lane + 64 * i;
        bool ok = (n < HW);
        float f = ok ? arow[n] : 0.0f;
        v[i] = f;
        uint32_t uu = __float_as_uint(f);
        uint32_t k = (uu & 0x80000000u) ? ~uu : (uu | 0x80000000u);
        key[i] = ok ? k : 0u;         // pad key 0: bin 0, never reachable by top-196
    }

    int kk = KSEL;
    uint32_t prefix = 0;

    // ---- round 0 (bits 31:24): exponent-clustered -> 4 padded sub-hists --
    {
        const int4 z4 = {0, 0, 0, 0};
        #pragma unroll
        for (int j = 0; j < 5; ++j) {
            int idx = lane + 64 * j;
            if (idx < 264) ((int4*)hp0)[idx] = z4;   // zero all 4*264 ints
        }
        __syncthreads();
        #pragma unroll
        for (int i = 0; i < NV; ++i)
            atomicAdd(&hist[wid][g][key[i] >> 24], 1);
        __syncthreads();
        int4 c0 = *(const int4*)&hist[wid][0][4 * lane];
        int4 c1 = *(const int4*)&hist[wid][1][4 * lane];
        int4 c2 = *(const int4*)&hist[wid][2][4 * lane];
        int4 c3 = *(const int4*)&hist[wid][3][4 * lane];
        int h0 = c0.x + c1.x + c2.x + c3.x;
        int h1 = c0.y + c1.y + c2.y + c3.y;
        int h2 = c0.z + c1.z + c2.z + c3.z;
        int h3 = c0.w + c1.w + c2.w + c3.w;
        int gsum = h0 + h1 + h2 + h3;
        int suf = gsum;
        #pragma unroll
        for (int off = 1; off < 64; off <<= 1) {
            int o = __shfl_down(suf, off, 64);
            suf += (lane + off < 64) ? o : 0;
        }
        int ex = suf - gsum;
        int cgt3 = ex, cgt2 = cgt3 + h3, cgt1 = cgt2 + h2, cgt0 = cgt1 + h1;
        int bsel = -1, cg = 0;
        if (cgt0 < kk && kk <= cgt0 + h0) { bsel = 4 * lane + 0; cg = cgt0; }
        if (cgt1 < kk && kk <= cgt1 + h1) { bsel = 4 * lane + 1; cg = cgt1; }
        if (cgt2 < kk && kk <= cgt2 + h2) { bsel = 4 * lane + 2; cg = cgt2; }
        if (cgt3 < kk && kk <= cgt3 + h3) { bsel = 4 * lane + 3; cg = cgt3; }
        unsigned long long m = __ballot(bsel >= 0);
        int src = (int)__ffsll((long long)m) - 1;
        bsel = __shfl(bsel, src, 64);
        cg   = __shfl(cg,   src, 64);
        kk -= cg;
        prefix = ((uint32_t)bsel) << 24;
        __syncthreads();
    }

    // ---- rounds 1..3: mantissa bits, few candidates -> single histogram --
    #pragma unroll
    for (int round = 1; round < 4; ++round) {
        const int shift = 24 - 8 * round;
        const uint32_t himask = 0xFFFFFFFFu << (shift + 8);
        const int4 z4 = {0, 0, 0, 0};
        ((int4*)hp0)[lane] = z4;      // zero 256 bins
        __syncthreads();
        #pragma unroll
        for (int i = 0; i < NV; ++i) {
            if ((key[i] & himask) == prefix)
                atomicAdd(&hp0[(key[i] >> shift) & 255], 1);
        }
        __syncthreads();
        int4 c = *(const int4*)&hp0[4 * lane];
        int h0 = c.x, h1 = c.y, h2 = c.z, h3 = c.w;
        int gsum = h0 + h1 + h2 + h3;
        int suf = gsum;
        #pragma unroll
        for (int off = 1; off < 64; off <<= 1) {
            int o = __shfl_down(suf, off, 64);
            suf += (lane + off < 64) ? o : 0;
        }
        int ex = suf - gsum;
        int cgt3 = ex, cgt2 = cgt3 + h3, cgt1 = cgt2 + h2, cgt0 = cgt1 + h1;
        int bsel = -1, cg = 0;
        if (cgt0 < kk && kk <= cgt0 + h0) { bsel = 4 * lane + 0; cg = cgt0; }
        if (cgt1 < kk && kk <= cgt1 + h1) { bsel = 4 * lane + 1; cg = cgt1; }
        if (cgt2 < kk && kk <= cgt2 + h2) { bsel = 4 * lane + 2; cg = cgt2; }
        if (cgt3 < kk && kk <= cgt3 + h3) { bsel = 4 * lane + 3; cg = cgt3; }
        unsigned long long m = __ballot(bsel >= 0);
        int src = (int)__ffsll((long long)m) - 1;
        bsel = __shfl(bsel, src, 64);
        cg   = __shfl(cg,   src, 64);
        kk -= cg;
        prefix |= ((uint32_t)bsel) << shift;
        __syncthreads();
    }

    uint32_t tu = (prefix & 0x80000000u) ? (prefix ^ 0x80000000u) : ~prefix;
    const float th = __uint_as_float(tu);

    float mx = -INFINITY;
    #pragma unroll
    for (int i = 0; i < NV; ++i) {
        int n = lane + 64 * i;
        float f = v[i];
        f = (f < th) ? 0.0f : f;
        v[i] = f;
        if (n < HW) mx = fmaxf(mx, f);
    }
    #pragma unroll
    for (int off = 32; off; off >>= 1) mx = fmaxf(mx, __shfl_xor(mx, off, 64));

    float sum = 0.f;
    #pragma unroll
    for (int i = 0; i < NV; ++i) {
        int n = lane + 64 * i;
        float e = __expf(v[i] - mx);
        v[i] = e;
        if (n < HW) sum += e;
    }
    #pragma unroll
    for (int off = 32; off; off >>= 1) sum += __shfl_xor(sum, off, 64);
    float inv = 1.0f / sum;

    float dot = 0.f;
    #pragma unroll
    for (int i = 0; i < NV; ++i) {
        int n = lane + 64 * i;
        if (n < HW) {
            float a = v[i] * inv;
            arow[n] = a;
            dot += xrow[n] * a;
        }
    }
    #pragma unroll
    for (int off = 32; off; off >>= 1) dot += __shfl_xor(dot, off, 64);
    if (lane == 0) out[row] = dot;
}

extern "C" void kernel_launch(void* const* d_in, const int* in_sizes, int n_in,
                              void* d_out, int out_size, void* d_ws, size_t ws_size,
                              hipStream_t stream) {
    const float* x    = (const float*)d_in[0];
    const float* s    = (const float*)d_in[1];
    const float* Wq_w = (const float*)d_in[2];
    const float* Wq_b = (const float*)d_in[3];
    const float* Uq_w = (const float*)d_in[4];
    const float* w_w  = (const float*)d_in[5];
    const float* w_b  = (const float*)d_in[6];
    float* out = (float*)d_out;

    f16* xt   = (f16*)d_ws;                                   // [25088][1024]
    f16* sig  = xt + (size_t)ROWS * INC;                      // [25088][256]
    f16* wq_h = sig + (size_t)ROWS * MIDC;                    // [256][1024]
    f16* ww_h = wq_h + MIDC * INC;                            // [1024][256]
    float* u  = (float*)(ww_h + INC * MIDC);                  // [32][256]
    float* alpha = out + BATCH * INC;                         // staged in atten slot

    cvt_f16<<<256, 256, 0, stream>>>(Wq_w, wq_h, MIDC * INC / 4);
    cvt_f16<<<256, 256, 0, stream>>>(w_w, ww_h, INC * MIDC / 4);
    prep_x<<<dim3(25, 32, 32), 256, 0, stream>>>(x, xt);
    calc_u<<<BATCH, 256, 0, stream>>>(s, Uq_w, Wq_b, u);
    gemm1_mfma<<<dim3(ROWS / 64, 2), 256, 0, stream>>>(wq_h, xt, u, sig);
    gemm2_mfma<<<dim3(ROWS / 128, 8), 256, 0, stream>>>(ww_h, sig, w_b, alpha);
    topk_softmax_reduce<<<BATCH * INC / 4, 256, 0, stream>>>(x, out);
}

// Round 6
// 179.366 us; speedup vs baseline: 6.0492x; 1.0274x over previous
//
#include <hip/hip_runtime.h>
#include <hip/hip_bf16.h>
#include <hip/hip_fp16.h>
#include <math.h>

#define BATCH 32
#define INC 1024
#define MIDC 256
#define SC 256
#define HW 784
#define ROWS 25088   // BATCH*HW
#define KSEL 196     // int(0.25 * 784)

typedef _Float16 f16;
typedef __attribute__((ext_vector_type(8))) _Float16 hfrag;  // 8 fp16 (4 VGPRs)
typedef __attribute__((ext_vector_type(4))) float f4;        // 4 fp32 acc

struct alignas(8) h4s { f16 x, y, z, w; };

__device__ inline float stanh_fast(float p) {
    // 1.7159*tanh(2p/3) = 1.7159*(1 - 2/(exp(4p/3)+1))
    float e = __expf(1.33333333f * p);
    return 1.7159f * (1.0f - 2.0f / (e + 1.0f));
}

// ---------------- fp32 -> fp16 weight convert (layout preserved) -----------
__global__ __launch_bounds__(256) void cvt_f16(const float* __restrict__ src,
                                               f16* __restrict__ dst, int n4) {
    int i = blockIdx.x * 256 + threadIdx.x;
    if (i >= n4) return;
    float4 v = ((const float4*)src)[i];
    h4s h = { (f16)v.x, (f16)v.y, (f16)v.z, (f16)v.w };
    ((h4s*)dst)[i] = h;
}

// ---------------- transpose x[b][c][n] -> xt[b][n][c] as fp16 --------------
__global__ __launch_bounds__(256) void prep_x(const float* __restrict__ x,
                                              f16* __restrict__ xh) {
    int b = blockIdx.z, c0 = blockIdx.y * 32, n0 = blockIdx.x * 32;
    __shared__ float tile[32][33];
    int t = threadIdx.x;
    int r = t >> 3, cg = (t & 7) * 4;
    if (n0 + cg + 3 < HW) {
        float4 v = *(const float4*)(x + (size_t)(b * INC + c0 + r) * HW + n0 + cg);
        tile[r][cg + 0] = v.x; tile[r][cg + 1] = v.y;
        tile[r][cg + 2] = v.z; tile[r][cg + 3] = v.w;
    }
    __syncthreads();
    int rn = t >> 3, cg2 = (t & 7) * 4;
    int n = n0 + rn;
    if (n < HW) {
        h4s h = { (f16)tile[cg2 + 0][rn], (f16)tile[cg2 + 1][rn],
                  (f16)tile[cg2 + 2][rn], (f16)tile[cg2 + 3][rn] };
        *(h4s*)(xh + ((size_t)b * HW + n) * INC + c0 + cg2) = h;
    }
}

// ---------------- u[b][m] = Wq_b[m] + Uq·s ---------------------------------
__global__ __launch_bounds__(256) void calc_u(const float* __restrict__ s,
                                              const float* __restrict__ Uq_w,
                                              const float* __restrict__ Wq_b,
                                              float* __restrict__ u) {
    __shared__ float ssh[SC];
    int b = blockIdx.x, m = threadIdx.x;
    ssh[m] = s[b * SC + m];
    __syncthreads();
    float acc = Wq_b[m];
    const float* uq = Uq_w + (size_t)m * SC;
    #pragma unroll 8
    for (int i = 0; i < SC; ++i) acc += ssh[i] * uq[i];
    u[b * MIDC + m] = acc;
}

// ---------------- GEMM1: sig_t[R][m] = stanh(Wq·xt[R] + u[R/784][m]) -------
__global__ __launch_bounds__(256) void gemm1_mfma(
    const f16* __restrict__ A,   // Wq [256][1024]
    const f16* __restrict__ B,   // xt [25088][1024]
    const float* __restrict__ u,
    f16* __restrict__ S) {       // sig [25088][256]
    const int R0 = blockIdx.x * 64;
    const int M0 = blockIdx.y * 128;
    __shared__ f16 Asm[128][40];
    __shared__ f16 Bsm[64][40];
    const int t = threadIdx.x;
    const int lane = t & 63, w = t >> 6;
    const int wc = (w >> 1) * 64;
    const int wr = (w & 1) * 32;
    const int ln = lane & 15, kg = lane >> 4;

    const int ar0 = t >> 2, ar1 = ar0 + 64;
    const int akc = (t & 3) * 8;
    const size_t aoff0 = (size_t)(M0 + ar0) * INC + akc;
    const size_t aoff1 = (size_t)(M0 + ar1) * INC + akc;
    const size_t boff  = (size_t)(R0 + ar0) * INC + akc;

    f4 acc[4][2];
    const f4 zero = {0.f, 0.f, 0.f, 0.f};
    #pragma unroll
    for (int i = 0; i < 4; ++i) { acc[i][0] = zero; acc[i][1] = zero; }

    hfrag rA0, rA1, rB;
    #define G1_LOAD(K0)                                   \
        rA0 = *(const hfrag*)(A + aoff0 + (K0));          \
        rA1 = *(const hfrag*)(A + aoff1 + (K0));          \
        rB  = *(const hfrag*)(B + boff  + (K0));

    G1_LOAD(0)
    for (int k0 = 0; k0 < INC; k0 += 32) {
        *(hfrag*)&Asm[ar0][akc] = rA0;
        *(hfrag*)&Asm[ar1][akc] = rA1;
        *(hfrag*)&Bsm[ar0][akc] = rB;
        __syncthreads();
        if (k0 + 32 < INC) { G1_LOAD(k0 + 32) }
        hfrag b0 = *(const hfrag*)&Bsm[wr + ln][kg * 8];
        hfrag b1 = *(const hfrag*)&Bsm[wr + 16 + ln][kg * 8];
        #pragma unroll
        for (int mi = 0; mi < 4; ++mi) {
            hfrag a = *(const hfrag*)&Asm[wc + mi * 16 + ln][kg * 8];
            acc[mi][0] = __builtin_amdgcn_mfma_f32_16x16x32_f16(a, b0, acc[mi][0], 0, 0, 0);
            acc[mi][1] = __builtin_amdgcn_mfma_f32_16x16x32_f16(a, b1, acc[mi][1], 0, 0, 0);
        }
        __syncthreads();
    }
    #undef G1_LOAD

    #pragma unroll
    for (int ni = 0; ni < 2; ++ni) {
        int R = R0 + wr + ni * 16 + ln;
        int b = R / HW;
        #pragma unroll
        for (int mi = 0; mi < 4; ++mi) {
            int mb = M0 + wc + mi * 16 + kg * 4;
            float uv[4];
            *(float4*)uv = *(const float4*)(u + b * MIDC + mb);
            h4s hv;
            hv.x = (f16)stanh_fast(acc[mi][ni][0] + uv[0]);
            hv.y = (f16)stanh_fast(acc[mi][ni][1] + uv[1]);
            hv.z = (f16)stanh_fast(acc[mi][ni][2] + uv[2]);
            hv.w = (f16)stanh_fast(acc[mi][ni][3] + uv[3]);
            *(h4s*)(S + (size_t)R * MIDC + mb) = hv;
        }
    }
}

// ---------------- GEMM2: alpha[b][c][n] = Ww·sig_t[R] + wb, R=(b,n) --------
__global__ __launch_bounds__(256) void gemm2_mfma(
    const f16* __restrict__ A,   // Ww [1024][256]
    const f16* __restrict__ B,   // sig [25088][256]
    const float* __restrict__ wb,
    float* __restrict__ aout) {
    const int R0 = blockIdx.x * 128;
    const int C0 = blockIdx.y * 128;
    __shared__ f16 Asm[128][40];
    __shared__ f16 Bsm[128][40];
    const int t = threadIdx.x;
    const int lane = t & 63, w = t >> 6;
    const int wc = (w >> 1) * 64;
    const int wr = (w & 1) * 64;
    const int ln = lane & 15, kg = lane >> 4;

    const int r0 = t >> 2, r1 = r0 + 64;
    const int kc = (t & 3) * 8;
    const size_t aoff0 = (size_t)(C0 + r0) * MIDC + kc;
    const size_t aoff1 = (size_t)(C0 + r1) * MIDC + kc;
    const size_t boff0 = (size_t)(R0 + r0) * MIDC + kc;
    const size_t boff1 = (size_t)(R0 + r1) * MIDC + kc;

    f4 acc[4][4];
    const f4 zero = {0.f, 0.f, 0.f, 0.f};
    #pragma unroll
    for (int i = 0; i < 4; ++i)
        #pragma unroll
        for (int j = 0; j < 4; ++j) acc[i][j] = zero;

    hfrag rA0, rA1, rB0, rB1;
    #define G2_LOAD(K0)                                   \
        rA0 = *(const hfrag*)(A + aoff0 + (K0));          \
        rA1 = *(const hfrag*)(A + aoff1 + (K0));          \
        rB0 = *(const hfrag*)(B + boff0 + (K0));          \
        rB1 = *(const hfrag*)(B + boff1 + (K0));

    G2_LOAD(0)
    for (int k0 = 0; k0 < MIDC; k0 += 32) {
        *(hfrag*)&Asm[r0][kc] = rA0;
        *(hfrag*)&Asm[r1][kc] = rA1;
        *(hfrag*)&Bsm[r0][kc] = rB0;
        *(hfrag*)&Bsm[r1][kc] = rB1;
        __syncthreads();
        if (k0 + 32 < MIDC) { G2_LOAD(k0 + 32) }
        hfrag bh[4];
        #pragma unroll
        for (int ni = 0; ni < 4; ++ni)
            bh[ni] = *(const hfrag*)&Bsm[wr + ni * 16 + ln][kg * 8];
        #pragma unroll
        for (int mi = 0; mi < 4; ++mi) {
            hfrag a = *(const hfrag*)&Asm[wc + mi * 16 + ln][kg * 8];
            #pragma unroll
            for (int ni = 0; ni < 4; ++ni)
                acc[mi][ni] = __builtin_amdgcn_mfma_f32_16x16x32_f16(a, bh[ni], acc[mi][ni], 0, 0, 0);
        }
        __syncthreads();
    }
    #undef G2_LOAD

    #pragma unroll
    for (int ni = 0; ni < 4; ++ni) {
        int R = R0 + wr + ni * 16 + ln;
        int b = R / HW;
        int n = R - b * HW;
        float* arow = aout + (size_t)b * INC * HW + n;
        #pragma unroll
        for (int mi = 0; mi < 4; ++mi) {
            int cb = C0 + wc + mi * 16 + kg * 4;
            float wv[4];
            *(float4*)wv = *(const float4*)(wb + cb);
            #pragma unroll
            for (int r = 0; r < 4; ++r)
                arow[(size_t)(cb + r) * HW] = acc[mi][ni][r] + wv[r];
        }
    }
}

// ---------------- per-(b,c) row: radix-select v3 ----------------------------
// Barrier-free (per-wave hist), float4 I/O, early-exit after any round when
// remaining rank hits bin boundary (kk==1 -> max of candidates, kk==hsel ->
// min of candidates). 16 value slots/lane; slot 3 only on lanes 0..3
// (784 = (3*64+4)*4). Pad keys = 0, excluded from atomics and reductions.
__global__ __launch_bounds__(256) void topk_softmax_reduce(const float* __restrict__ x,
                                                           float* __restrict__ out) {
    const int wid  = threadIdx.x >> 6;
    const int lane = threadIdx.x & 63;
    const int row  = blockIdx.x * 4 + wid;
    float* arow = out + BATCH * INC + (size_t)row * HW;
    const float* xrow = x + (size_t)row * HW;

    __shared__ int hist[4][4][264];   // [wave][subgroup][bin(+pad)]
    int* hp0 = &hist[wid][0][0];
    const int g = lane >> 4;

    const bool has3 = (lane < 4);
    float4 v4[4];
    uint32_t key[16];

    {   // vectorized load of the row (196 float4 chunks)
        const float4* ap = (const float4*)arow;
        v4[0] = ap[lane];
        v4[1] = ap[lane + 64];
        v4[2] = ap[lane + 128];
        v4[3] = has3 ? ap[192 + lane] : make_float4(0.f, 0.f, 0.f, 0.f);
    }
    const float* vv = (const float*)v4;
    #pragma unroll
    for (int i = 0; i < 16; ++i) {
        bool ok = (i < 12) | has3;
        uint32_t uu = __float_as_uint(vv[i]);
        uint32_t k = (uu & 0x80000000u) ? ~uu : (uu | 0x80000000u);
        key[i] = ok ? k : 0u;
    }

    int kk = KSEL;
    uint32_t prefix = 0;
    uint32_t thkey = 0;
    bool done = false;

    #pragma unroll
    for (int round = 0; round < 4; ++round) {
        if (!done) {
            const int shift = 24 - 8 * round;
            const int4 z4 = {0, 0, 0, 0};
            if (round == 0) {
                #pragma unroll
                for (int j = 0; j < 5; ++j) {
                    int idx = lane + 64 * j;
                    if (idx < 264) ((int4*)hp0)[idx] = z4;
                }
                #pragma unroll
                for (int i = 0; i < 16; ++i)
                    if (key[i]) atomicAdd(&hist[wid][g][key[i] >> 24], 1);
            } else {
                ((int4*)hp0)[lane] = z4;
                const uint32_t himask = 0xFFFFFFFFu << (shift + 8);
                #pragma unroll
                for (int i = 0; i < 16; ++i)
                    if ((key[i] & himask) == prefix)
                        atomicAdd(&hp0[(key[i] >> shift) & 255], 1);
            }

            int h0, h1, h2, h3;
            if (round == 0) {
                int4 c0 = *(const int4*)&hist[wid][0][4 * lane];
                int4 c1 = *(const int4*)&hist[wid][1][4 * lane];
                int4 c2 = *(const int4*)&hist[wid][2][4 * lane];
                int4 c3 = *(const int4*)&hist[wid][3][4 * lane];
                h0 = c0.x + c1.x + c2.x + c3.x;
                h1 = c0.y + c1.y + c2.y + c3.y;
                h2 = c0.z + c1.z + c2.z + c3.z;
                h3 = c0.w + c1.w + c2.w + c3.w;
            } else {
                int4 c = *(const int4*)&hp0[4 * lane];
                h0 = c.x; h1 = c.y; h2 = c.z; h3 = c.w;
            }
            int gsum = h0 + h1 + h2 + h3;
            int suf = gsum;
            #pragma unroll
            for (int off = 1; off < 64; off <<= 1) {
                int o = __shfl_down(suf, off, 64);
                suf += (lane + off < 64) ? o : 0;
            }
            int ex = suf - gsum;
            int cgt3 = ex, cgt2 = cgt3 + h3, cgt1 = cgt2 + h2, cgt0 = cgt1 + h1;
            int bsel = -1, cg = 0, hs = 0;
            if (cgt0 < kk && kk <= cgt0 + h0) { bsel = 4 * lane + 0; cg = cgt0; hs = h0; }
            if (cgt1 < kk && kk <= cgt1 + h1) { bsel = 4 * lane + 1; cg = cgt1; hs = h1; }
            if (cgt2 < kk && kk <= cgt2 + h2) { bsel = 4 * lane + 2; cg = cgt2; hs = h2; }
            if (cgt3 < kk && kk <= cgt3 + h3) { bsel = 4 * lane + 3; cg = cgt3; hs = h3; }
            unsigned long long m = __ballot(bsel >= 0);
            int src = (int)__ffsll((long long)m) - 1;
            bsel = __shfl(bsel, src, 64);
            cg   = __shfl(cg,   src, 64);
            hs   = __shfl(hs,   src, 64);
            kk -= cg;
            prefix |= ((uint32_t)bsel) << shift;

            if (shift == 0) {
                thkey = prefix;
                done = true;
            } else if (kk == 1 || kk == hs) {
                // threshold = max (kk==1) or min (kk==hs) of candidates
                const uint32_t maskP = 0xFFFFFFFFu << shift;
                bool want_max = (kk == 1);
                uint32_t r = want_max ? 0u : 0xFFFFFFFFu;
                #pragma unroll
                for (int i = 0; i < 16; ++i) {
                    if ((key[i] & maskP) == prefix)
                        r = want_max ? (r > key[i] ? r : key[i])
                                     : (r < key[i] ? r : key[i]);
                }
                #pragma unroll
                for (int off = 32; off; off >>= 1) {
                    uint32_t o = __shfl_xor(r, off, 64);
                    r = want_max ? (r > o ? r : o) : (r < o ? r : o);
                }
                thkey = r;
                done = true;
            }
        }
    }

    uint32_t tu = (thkey & 0x80000000u) ? (thkey ^ 0x80000000u) : ~thkey;
    const float th = __uint_as_float(tu);

    // mask + max
    float* vw = (float*)v4;
    float mx = -INFINITY;
    #pragma unroll
    for (int i = 0; i < 16; ++i) {
        bool ok = (i < 12) | has3;
        float f = vw[i];
        f = (f < th) ? 0.0f : f;
        vw[i] = f;
        if (ok) mx = fmaxf(mx, f);
    }
    #pragma unroll
    for (int off = 32; off; off >>= 1) mx = fmaxf(mx, __shfl_xor(mx, off, 64));

    // exp + sum
    float sum = 0.f;
    #pragma unroll
    for (int i = 0; i < 16; ++i) {
        bool ok = (i < 12) | has3;
        float e = __expf(vw[i] - mx);
        vw[i] = e;
        sum += ok ? e : 0.f;
    }
    #pragma unroll
    for (int off = 32; off; off >>= 1) sum += __shfl_xor(sum, off, 64);
    float inv = 1.0f / sum;

    // normalize + store atten + weighted reduce against x
    float dot = 0.f;
    {
        float4* ap = (float4*)arow;
        const float4* xp = (const float4*)xrow;
        #pragma unroll
        for (int ci = 0; ci < 4; ++ci) {
            if (ci == 3 && !has3) break;
            int chunk = (ci < 3) ? (lane + 64 * ci) : (192 + lane);
            float4 a;
            a.x = vw[ci * 4 + 0] * inv;
            a.y = vw[ci * 4 + 1] * inv;
            a.z = vw[ci * 4 + 2] * inv;
            a.w = vw[ci * 4 + 3] * inv;
            ap[chunk] = a;
            float4 xl = xp[chunk];
            dot += xl.x * a.x + xl.y * a.y + xl.z * a.z + xl.w * a.w;
        }
    }
    #pragma unroll
    for (int off = 32; off; off >>= 1) dot += __shfl_xor(dot, off, 64);
    if (lane == 0) out[row] = dot;
}

extern "C" void kernel_launch(void* const* d_in, const int* in_sizes, int n_in,
                              void* d_out, int out_size, void* d_ws, size_t ws_size,
                              hipStream_t stream) {
    const float* x    = (const float*)d_in[0];
    const float* s    = (const float*)d_in[1];
    const float* Wq_w = (const float*)d_in[2];
    const float* Wq_b = (const float*)d_in[3];
    const float* Uq_w = (const float*)d_in[4];
    const float* w_w  = (const float*)d_in[5];
    const float* w_b  = (const float*)d_in[6];
    float* out = (float*)d_out;

    f16* xt   = (f16*)d_ws;                                   // [25088][1024]
    f16* sig  = xt + (size_t)ROWS * INC;                      // [25088][256]
    f16* wq_h = sig + (size_t)ROWS * MIDC;                    // [256][1024]
    f16* ww_h = wq_h + MIDC * INC;                            // [1024][256]
    float* u  = (float*)(ww_h + INC * MIDC);                  // [32][256]
    float* alpha = out + BATCH * INC;                         // staged in atten slot

    cvt_f16<<<256, 256, 0, stream>>>(Wq_w, wq_h, MIDC * INC / 4);
    cvt_f16<<<256, 256, 0, stream>>>(w_w, ww_h, INC * MIDC / 4);
    prep_x<<<dim3(25, 32, 32), 256, 0, stream>>>(x, xt);
    calc_u<<<BATCH, 256, 0, stream>>>(s, Uq_w, Wq_b, u);
    gemm1_mfma<<<dim3(ROWS / 64, 2), 256, 0, stream>>>(wq_h, xt, u, sig);
    gemm2_mfma<<<dim3(ROWS / 128, 8), 256, 0, stream>>>(ww_h, sig, w_b, alpha);
    topk_softmax_reduce<<<BATCH * INC / 4, 256, 0, stream>>>(x, out);
}